// Round 12
// baseline (522.819 us; speedup 1.0000x reference)
//
#include <hip/hip_runtime.h>

// Decoder block: x -> LN1 -> QKV GEMM -> causal MHA -> proj(+x) -> LN2 -> FFN(+res)
// B=4 T=2048 C=1024 H=16 hd=64.  All MFMA compute in bf16, fp32 accumulate.

typedef __attribute__((ext_vector_type(8))) short shortx8;   // 8 bf16 (4 VGPR)
typedef __attribute__((ext_vector_type(4))) float floatx4;   // MFMA C/D

__device__ __forceinline__ short f2bf(float f) {
  unsigned u = __builtin_bit_cast(unsigned, f);
  u = (u + 0x7fffu + ((u >> 16) & 1u)) >> 16;   // RNE
  return (short)u;
}
__device__ __forceinline__ float bf2f(short s) {
  return __builtin_bit_cast(float, (unsigned)((unsigned short)s) << 16);
}

// ---- weight transpose + cast: in [K][N] f32 -> out [N][K] bf16 ----
__global__ __launch_bounds__(256)
void transpose_cast(const float* __restrict__ in, short* __restrict__ out,
                    int K, int N) {
  __shared__ float tile[32][33];
  const int n0 = blockIdx.x * 32, k0 = blockIdx.y * 32;
  const int tx = threadIdx.x & 31, ty = threadIdx.x >> 5;  // 32x8
  for (int i = 0; i < 32; i += 8)
    tile[ty + i][tx] = in[(size_t)(k0 + ty + i) * N + n0 + tx];
  __syncthreads();
  for (int i = 0; i < 32; i += 8)
    out[(size_t)(n0 + ty + i) * K + k0 + tx] = f2bf(tile[tx][ty + i]);
}

// ---- layernorm: f32 in -> bf16 out, C=1024, one block (256 thr) per row ----
__global__ __launch_bounds__(256)
void layernorm_kernel(const float* __restrict__ x, const float* __restrict__ w,
                      const float* __restrict__ bta, short* __restrict__ out) {
  const int C = 1024;
  const int row = blockIdx.x;
  const float4 v = ((const float4*)(x + (size_t)row * C))[threadIdx.x];
  float s1 = v.x + v.y + v.z + v.w;
  float s2 = v.x * v.x + v.y * v.y + v.z * v.z + v.w * v.w;
  for (int m = 1; m < 64; m <<= 1) { s1 += __shfl_xor(s1, m); s2 += __shfl_xor(s2, m); }
  __shared__ float r1[4], r2[4];
  const int wid = threadIdx.x >> 6, lane = threadIdx.x & 63;
  if (lane == 0) { r1[wid] = s1; r2[wid] = s2; }
  __syncthreads();
  s1 = r1[0] + r1[1] + r1[2] + r1[3];
  s2 = r2[0] + r2[1] + r2[2] + r2[3];
  const float mean = s1 * (1.0f / C);
  const float var = s2 * (1.0f / C) - mean * mean;
  const float rs = rsqrtf(var + 1e-5f);
  const float4 wv = ((const float4*)w)[threadIdx.x];
  const float4 bv = ((const float4*)bta)[threadIdx.x];
  short4 o;
  o.x = f2bf((v.x - mean) * rs * wv.x + bv.x);
  o.y = f2bf((v.y - mean) * rs * wv.y + bv.y);
  o.z = f2bf((v.z - mean) * rs * wv.z + bv.z);
  o.w = f2bf((v.w - mean) * rs * wv.w + bv.w);
  *(short4*)(out + (size_t)row * C + threadIdx.x * 4) = o;
}

// ---- MFMA GEMM: C = A[M,K]@Bt[N,K]^T + bias (+resid)(+relu)
// 128x128 tile, BK=64 as TWO independent BK=32 sub-tiles.  Used by qkv/ff1
// (grids 1536/2048 = 6-8 blocks/CU).  R2: BK=64 halves the barrier drains.
// NOTE (R11 post-mortem): total-duration deltas across sessions have ~±15us
// noise (R6 vs R11: identical GEMM source, profile clocks differ); trust
// per-dispatch counters only.  FLAGS: bit0=relu, bit1=resid(fp32).
template<int FLAGS, typename OutT>
__global__ __launch_bounds__(256, 4)
void gemm_bt(const short* __restrict__ A, int lda,
             const short* __restrict__ Bt, int ldb,
             const float* __restrict__ bias, const float* __restrict__ resid,
             OutT* __restrict__ C, int M, int N, int K) {
  constexpr bool RELU = (FLAGS & 1) != 0;
  constexpr bool RESID = (FLAGS & 2) != 0;
  __shared__ short As[2][128 * 32];   // [khalf][m][k]
  __shared__ short Bs[2][128 * 32];   // [khalf][n][k]
  int bmi, bni;
  {
    const int nb = gridDim.x, mb = gridDim.y;
    const int g = blockIdx.x + nb * blockIdx.y;
    if ((mb & 7) == 0) {
      const int xcd = g & 7, l = g >> 3;      // 8 XCDs, round-robin dispatch
      bmi = xcd * (mb >> 3) + l / nb;
      bni = l % nb;
    } else { bmi = blockIdx.y; bni = blockIdx.x; }
  }
  const int bm0 = bmi * 128, bn0 = bni * 128;
  const int tid = threadIdx.x, wid = tid >> 6, lane = tid & 63;
  const int quad = lane >> 4, l15 = lane & 15;
  const int wm = wid & 1, wn = wid >> 1;
  const int srow = lane >> 2, scol = (lane & 3) * 8;
  floatx4 acc[4][4] = {};
  for (int k0 = 0; k0 < K; k0 += 64) {
    for (int i = 0; i < 2; ++i) {
      const int r0 = (wid * 2 + i) * 16;
      const short* ga = A + (size_t)(bm0 + r0 + srow) * lda + k0 + scol;
      const short* gb = Bt + (size_t)(bn0 + r0 + srow) * ldb + k0 + scol;
      __builtin_amdgcn_global_load_lds(
          (const __attribute__((address_space(1))) void*)ga,
          (__attribute__((address_space(3))) void*)&As[0][r0 * 32], 16, 0, 0);
      __builtin_amdgcn_global_load_lds(
          (const __attribute__((address_space(1))) void*)(ga + 32),
          (__attribute__((address_space(3))) void*)&As[1][r0 * 32], 16, 0, 0);
      __builtin_amdgcn_global_load_lds(
          (const __attribute__((address_space(1))) void*)gb,
          (__attribute__((address_space(3))) void*)&Bs[0][r0 * 32], 16, 0, 0);
      __builtin_amdgcn_global_load_lds(
          (const __attribute__((address_space(1))) void*)(gb + 32),
          (__attribute__((address_space(3))) void*)&Bs[1][r0 * 32], 16, 0, 0);
    }
    asm volatile("s_waitcnt vmcnt(0)" ::: "memory");
    __syncthreads();
    // half 0
    {
      shortx8 af[4], bfr[4];
#pragma unroll
      for (int i = 0; i < 4; ++i)
        af[i] = *(const shortx8*)&As[0][(wm * 64 + i * 16 + l15) * 32 + quad * 8];
#pragma unroll
      for (int j = 0; j < 4; ++j)
        bfr[j] = *(const shortx8*)&Bs[0][(wn * 64 + j * 16 + l15) * 32 + quad * 8];
#pragma unroll
      for (int i = 0; i < 4; ++i)
#pragma unroll
        for (int j = 0; j < 4; ++j)
          acc[i][j] = __builtin_amdgcn_mfma_f32_16x16x32_bf16(af[i], bfr[j], acc[i][j], 0, 0, 0);
    }
    // half 1
    {
      shortx8 af[4], bfr[4];
#pragma unroll
      for (int i = 0; i < 4; ++i)
        af[i] = *(const shortx8*)&As[1][(wm * 64 + i * 16 + l15) * 32 + quad * 8];
#pragma unroll
      for (int j = 0; j < 4; ++j)
        bfr[j] = *(const shortx8*)&Bs[1][(wn * 64 + j * 16 + l15) * 32 + quad * 8];
#pragma unroll
      for (int i = 0; i < 4; ++i)
#pragma unroll
        for (int j = 0; j < 4; ++j)
          acc[i][j] = __builtin_amdgcn_mfma_f32_16x16x32_bf16(af[i], bfr[j], acc[i][j], 0, 0, 0);
    }
    __syncthreads();
  }
  // epilogue: D row = (lane>>4)*4 + reg, col = lane&15 (m89/m91-verified)
#pragma unroll
  for (int i = 0; i < 4; ++i) {
    const int row = bm0 + wm * 64 + i * 16 + quad * 4;
#pragma unroll
    for (int j = 0; j < 4; ++j) {
      const int col = bn0 + wn * 64 + j * 16 + l15;
      const float bb = bias[col];
#pragma unroll
      for (int r = 0; r < 4; ++r) {
        float v = acc[i][j][r] + bb;
        if (RELU) v = fmaxf(v, 0.0f);
        if (RESID) v += resid[(size_t)(row + r) * N + col];
        if constexpr (sizeof(OutT) == 2)
          C[(size_t)(row + r) * N + col] = f2bf(v);
        else
          C[(size_t)(row + r) * N + col] = v;
      }
    }
  }
}

// ---- BN=64 GEMM variant for the GRID-STARVED GEMMs (proj, ff2: N=1024) ----
// 128x64 tile, 4 waves as 2x2 over 64x32 sub-tiles, acc[4][2], Bs halved.
// Grid (16,64) = 1024 blocks = 4 blocks/CU (vs 2 at BN=128): doubles the
// waves available to cover each vmcnt(0)+barrier drain.  Cost: A re-read by
// 16 col-tiles instead of 8 (+~50MB on ff2; we run at 16% HBM, L2-absorbed).
// Separate hand-written function (not a gemm_bt instantiation).
template<int FLAGS, typename OutT>
__global__ __launch_bounds__(256, 4)
void gemm_bt_n64(const short* __restrict__ A, int lda,
                 const short* __restrict__ Bt, int ldb,
                 const float* __restrict__ bias, const float* __restrict__ resid,
                 OutT* __restrict__ C, int M, int N, int K) {
  constexpr bool RELU = (FLAGS & 1) != 0;
  constexpr bool RESID = (FLAGS & 2) != 0;
  __shared__ short As[2][128 * 32];   // [khalf][m][k]
  __shared__ short Bs[2][64 * 32];    // [khalf][n][k]
  int bmi, bni;
  {
    const int nb = gridDim.x, mb = gridDim.y;
    const int g = blockIdx.x + nb * blockIdx.y;
    if ((mb & 7) == 0) {
      const int xcd = g & 7, l = g >> 3;
      bmi = xcd * (mb >> 3) + l / nb;
      bni = l % nb;
    } else { bmi = blockIdx.y; bni = blockIdx.x; }
  }
  const int bm0 = bmi * 128, bn0 = bni * 64;
  const int tid = threadIdx.x, wid = tid >> 6, lane = tid & 63;
  const int quad = lane >> 4, l15 = lane & 15;
  const int wm = wid & 1, wn = wid >> 1;          // 2x2 waves over 64x32
  const int srow = lane >> 2, scol = (lane & 3) * 8;
  floatx4 acc[4][2] = {};
  for (int k0 = 0; k0 < K; k0 += 64) {
    for (int i = 0; i < 2; ++i) {
      const int r0 = (wid * 2 + i) * 16;
      const short* ga = A + (size_t)(bm0 + r0 + srow) * lda + k0 + scol;
      __builtin_amdgcn_global_load_lds(
          (const __attribute__((address_space(1))) void*)ga,
          (__attribute__((address_space(3))) void*)&As[0][r0 * 32], 16, 0, 0);
      __builtin_amdgcn_global_load_lds(
          (const __attribute__((address_space(1))) void*)(ga + 32),
          (__attribute__((address_space(3))) void*)&As[1][r0 * 32], 16, 0, 0);
    }
    {
      const int r0b = wid * 16;                   // 4 waves cover 64 B rows
      const short* gb = Bt + (size_t)(bn0 + r0b + srow) * ldb + k0 + scol;
      __builtin_amdgcn_global_load_lds(
          (const __attribute__((address_space(1))) void*)gb,
          (__attribute__((address_space(3))) void*)&Bs[0][r0b * 32], 16, 0, 0);
      __builtin_amdgcn_global_load_lds(
          (const __attribute__((address_space(1))) void*)(gb + 32),
          (__attribute__((address_space(3))) void*)&Bs[1][r0b * 32], 16, 0, 0);
    }
    asm volatile("s_waitcnt vmcnt(0)" ::: "memory");
    __syncthreads();
    // half 0
    {
      shortx8 af[4], bfr[2];
#pragma unroll
      for (int i = 0; i < 4; ++i)
        af[i] = *(const shortx8*)&As[0][(wm * 64 + i * 16 + l15) * 32 + quad * 8];
#pragma unroll
      for (int j = 0; j < 2; ++j)
        bfr[j] = *(const shortx8*)&Bs[0][(wn * 32 + j * 16 + l15) * 32 + quad * 8];
#pragma unroll
      for (int i = 0; i < 4; ++i)
#pragma unroll
        for (int j = 0; j < 2; ++j)
          acc[i][j] = __builtin_amdgcn_mfma_f32_16x16x32_bf16(af[i], bfr[j], acc[i][j], 0, 0, 0);
    }
    // half 1
    {
      shortx8 af[4], bfr[2];
#pragma unroll
      for (int i = 0; i < 4; ++i)
        af[i] = *(const shortx8*)&As[1][(wm * 64 + i * 16 + l15) * 32 + quad * 8];
#pragma unroll
      for (int j = 0; j < 2; ++j)
        bfr[j] = *(const shortx8*)&Bs[1][(wn * 32 + j * 16 + l15) * 32 + quad * 8];
#pragma unroll
      for (int i = 0; i < 4; ++i)
#pragma unroll
        for (int j = 0; j < 2; ++j)
          acc[i][j] = __builtin_amdgcn_mfma_f32_16x16x32_bf16(af[i], bfr[j], acc[i][j], 0, 0, 0);
    }
    __syncthreads();
  }
#pragma unroll
  for (int i = 0; i < 4; ++i) {
    const int row = bm0 + wm * 64 + i * 16 + quad * 4;
#pragma unroll
    for (int j = 0; j < 2; ++j) {
      const int col = bn0 + wn * 32 + j * 16 + l15;
      const float bb = bias[col];
#pragma unroll
      for (int r = 0; r < 4; ++r) {
        float v = acc[i][j][r] + bb;
        if (RELU) v = fmaxf(v, 0.0f);
        if (RESID) v += resid[(size_t)(row + r) * N + col];
        if constexpr (sizeof(OutT) == 2)
          C[(size_t)(row + r) * N + col] = f2bf(v);
        else
          C[(size_t)(row + r) * N + col] = v;
      }
    }
  }
}

// ================= split-K flash attention =================
// Static-max softmax (scores = q.k/32, tiny; fp32 exp2 has huge headroom) makes
// chunk partials ADDITIVE: O_unnorm = sum P.V, lsum = sum p.  Each block does
// one (qb, h, b, key-chunk of <=8 tiles).  qb<8 (single chunk) writes final
// bf16 y directly; else partials go to ws and attn_reduce sums & normalizes.
//
// R3: P stored k-PERMUTED for v_cvt_pk_bf16_f32; Vt key rows permuted
// identically (exact: PV sums over k).
// R6: raw v_exp_f32, wave-uniform diag split, v_rcp_f32.  98.5 -> 88.4us.
// R8/R9 (two-tile pairing) FAILED correctness twice — retired.
// R11: bf16 O partials (lsum fp32) — WRITE_SIZE 79->42MB, verified exact
// enough (absmax unchanged at 0.031).
#define ATTN_SLOTS 80           // sum over qb of ceil((qb+1)/8)
#define ATTN_SLOT_SH 4224       // shorts per slot: 64*64 bf16 O + 64 fp32 lsum

__global__ __launch_bounds__(256)
void attention_chunk(const short* __restrict__ qkv, short* __restrict__ y,
                     float* __restrict__ part) {
  constexpr int T = 2048, C = 1024, HD = 64, S3 = 3072;
  __shared__ short Ks[64 * 72];      // [key][d], pad 72
  __shared__ short Vt[64 * 72];      // [d][k'], permuted keys, pad 72
  __shared__ short Ps[4][16 * 72];   // per-wave P: [q][k'], permuted
  const int x = blockIdx.x, h = blockIdx.y, b = blockIdx.z;
  int qb, ch;
  if (x < 8)       { qb = x;                 ch = 0; }
  else if (x < 24) { qb = 8 + ((x - 8) >> 1);  ch = (x - 8) & 1; }
  else if (x < 48) { qb = 16 + (x - 24) / 3;   ch = (x - 24) % 3; }
  else             { qb = 24 + ((x - 48) >> 2); ch = (x - 48) & 3; }
  const int kt0 = ch * 8;
  const int kt1 = min(kt0 + 8, qb + 1);
  const int tid = threadIdx.x, wid = tid >> 6, lane = tid & 63;
  const int quad = lane >> 4, l15 = lane & 15;
  const size_t base = (size_t)b * T * S3;
  const int q0 = qb * 64 + wid * 16;
  // Q A-frags: A[m=lane&15][k=quad*8+j]
  const short* Qp = qkv + base + (size_t)(q0 + l15) * S3 + h * HD;
  const shortx8 qf0 = *(const shortx8*)(Qp + quad * 8);
  const shortx8 qf1 = *(const shortx8*)(Qp + 32 + quad * 8);
  floatx4 o[4] = {};
  float lsum[4] = {0.f, 0.f, 0.f, 0.f};
  const float scale2 = 0.03125f * 1.44269504088896f;  // 1/sqrt(C) * log2(e)
  const int skey = tid >> 2, sd = (tid & 3) * 16;  // K staging
  const int vkp = tid & 31, vdb = tid >> 5;        // V staging (vdb 0..7)
  const int vkE = (vkp >> 4) * 32 + (vkp & 15);    // even-k' source key row
  const short* Kbase = qkv + base + C + h * HD;
  const short* Vbase = qkv + base + 2 * C + h * HD;
  // register prefetch of tile kt0
  shortx8 pk0, pk1, pv0, pv1;
  {
    const short* Kp = Kbase + (size_t)(kt0 * 64 + skey) * S3 + sd;
    pk0 = *(const shortx8*)Kp;
    pk1 = *(const shortx8*)(Kp + 8);
    const short* Vp = Vbase + (size_t)(kt0 * 64 + vkE) * S3 + vdb * 8;
    pv0 = *(const shortx8*)Vp;            // key c   -> k' even (lo)
    pv1 = *(const shortx8*)(Vp + 16 * S3);// key c+16 -> k' odd (hi)
  }
  for (int kt = kt0; kt < kt1; ++kt) {
    const int key0 = kt * 64;
    __syncthreads();
    *(shortx8*)&Ks[skey * 72 + sd] = pk0;
    *(shortx8*)&Ks[skey * 72 + sd + 8] = pk1;
#pragma unroll
    for (int j = 0; j < 8; ++j) {
      short2 pr = make_short2(pv0[j], pv1[j]);
      *(short2*)&Vt[(vdb * 8 + j) * 72 + 2 * vkp] = pr;
    }
    __syncthreads();
    if (kt + 1 < kt1) {  // prefetch next tile
      const int kn = key0 + 64;
      const short* Kp = Kbase + (size_t)(kn + skey) * S3 + sd;
      pk0 = *(const shortx8*)Kp;
      pk1 = *(const shortx8*)(Kp + 8);
      const short* Vp = Vbase + (size_t)(kn + vkE) * S3 + vdb * 8;
      pv0 = *(const shortx8*)Vp;
      pv1 = *(const shortx8*)(Vp + 16 * S3);
    }
    floatx4 s[4];
#pragma unroll
    for (int nt = 0; nt < 4; ++nt) {
      const short* kb = &Ks[(nt * 16 + l15) * 72 + quad * 8];
      floatx4 a = {};
      a = __builtin_amdgcn_mfma_f32_16x16x32_bf16(qf0, *(const shortx8*)kb, a, 0, 0, 0);
      a = __builtin_amdgcn_mfma_f32_16x16x32_bf16(qf1, *(const shortx8*)(kb + 32), a, 0, 0, 0);
      s[nt] = a;
    }
    short* pw = &Ps[wid][0];
    if (kt != qb) {   // fast path: no causal mask in this tile (wave-uniform)
#pragma unroll
      for (int r = 0; r < 4; ++r) {
        const float p0 = __builtin_amdgcn_exp2f(s[0][r] * scale2);
        const float p1 = __builtin_amdgcn_exp2f(s[1][r] * scale2);
        const float p2 = __builtin_amdgcn_exp2f(s[2][r] * scale2);
        const float p3 = __builtin_amdgcn_exp2f(s[3][r] * scale2);
        lsum[r] += (p0 + p1) + (p2 + p3);
        unsigned w0, w1;
        asm("v_cvt_pk_bf16_f32 %0, %1, %2" : "=v"(w0) : "v"(p0), "v"(p1));
        asm("v_cvt_pk_bf16_f32 %0, %1, %2" : "=v"(w1) : "v"(p2), "v"(p3));
        unsigned* prow = (unsigned*)&pw[(quad * 4 + r) * 72];
        prow[l15] = w0;        // k' = 2*l15, 2*l15+1        (cols l15, l15+16)
        prow[16 + l15] = w1;   // k' = 32+2*l15, 32+2*l15+1  (cols l15+32, l15+48)
      }
    } else {          // diag tile: mask key > q
#pragma unroll
      for (int r = 0; r < 4; ++r) {
        const int q = q0 + quad * 4 + r;
        float pr[4];
#pragma unroll
        for (int nt = 0; nt < 4; ++nt) {
          float sv = s[nt][r] * scale2;
          if (key0 + nt * 16 + l15 > q) sv = -INFINITY;
          pr[nt] = __builtin_amdgcn_exp2f(sv);  // v_exp_f32(-inf)=0
        }
        lsum[r] += (pr[0] + pr[1]) + (pr[2] + pr[3]);
        unsigned w0, w1;
        asm("v_cvt_pk_bf16_f32 %0, %1, %2" : "=v"(w0) : "v"(pr[0]), "v"(pr[1]));
        asm("v_cvt_pk_bf16_f32 %0, %1, %2" : "=v"(w1) : "v"(pr[2]), "v"(pr[3]));
        unsigned* prow = (unsigned*)&pw[(quad * 4 + r) * 72];
        prow[l15] = w0;
        prow[16 + l15] = w1;
      }
    }
    asm volatile("s_waitcnt lgkmcnt(0)" ::: "memory");
#pragma unroll
    for (int kf = 0; kf < 2; ++kf) {
      const shortx8 pa = *(const shortx8*)&Ps[wid][l15 * 72 + kf * 32 + quad * 8];
#pragma unroll
      for (int dt = 0; dt < 4; ++dt) {
        const shortx8 vb = *(const shortx8*)&Vt[(dt * 16 + l15) * 72 + kf * 32 + quad * 8];
        o[dt] = __builtin_amdgcn_mfma_f32_16x16x32_bf16(pa, vb, o[dt], 0, 0, 0);
      }
    }
  }
  // reduce lsum over the 16 lanes of each quad group
  float ls[4];
#pragma unroll
  for (int r = 0; r < 4; ++r) {
    float s = lsum[r];
    for (int off = 1; off < 16; off <<= 1) s += __shfl_xor(s, off);
    ls[r] = s;
  }
  if (x < 8) {  // single chunk -> final output
    float inv[4];
#pragma unroll
    for (int r = 0; r < 4; ++r) inv[r] = __builtin_amdgcn_rcpf(ls[r]);
#pragma unroll
    for (int dt = 0; dt < 4; ++dt)
#pragma unroll
      for (int r = 0; r < 4; ++r) {
        const int q = q0 + quad * 4 + r;
        y[((size_t)b * T + q) * C + h * HD + dt * 16 + l15] =
            f2bf(o[dt][r] * inv[r]);
      }
  } else {      // bf16 O partials + fp32 lsum
    short* pp = (short*)part +
                ((size_t)(b * 16 + h) * ATTN_SLOTS + x) * ATTN_SLOT_SH;
    float* pl = (float*)(pp + 4096);
    const int qw = wid * 16;
#pragma unroll
    for (int dt = 0; dt < 4; ++dt)
#pragma unroll
      for (int r = 0; r < 4; ++r)
        pp[(qw + quad * 4 + r) * 64 + dt * 16 + l15] = f2bf(o[dt][r]);
    if (l15 == 0)
#pragma unroll
      for (int r = 0; r < 4; ++r)
        pl[qw + quad * 4 + r] = ls[r];
  }
}

__global__ __launch_bounds__(256)
void attn_reduce(const float* __restrict__ part, short* __restrict__ y) {
  constexpr int T = 2048, C = 1024;
  const int qb = 8 + blockIdx.x, h = blockIdx.y, b = blockIdx.z;
  const int c = qb / 8 + 1;  // 2..4 chunks
  int slot0;
  if (qb < 16)      slot0 = 8 + 2 * (qb - 8);
  else if (qb < 24) slot0 = 24 + 3 * (qb - 16);
  else              slot0 = 48 + 4 * (qb - 24);
  const short* rb = (const short*)part +
                    ((size_t)(b * 16 + h) * ATTN_SLOTS + slot0) * ATTN_SLOT_SH;
  const int t = threadIdx.x;
  const int q = t >> 2, dg = (t & 3) * 16;
  float acc[16] = {};
  float ls = 0.f;
  for (int ci = 0; ci < c; ++ci) {
    const short* pp = rb + (size_t)ci * ATTN_SLOT_SH;
    const shortx8 v0 = *(const shortx8*)(pp + q * 64 + dg);
    const shortx8 v1 = *(const shortx8*)(pp + q * 64 + dg + 8);
#pragma unroll
    for (int i = 0; i < 8; ++i) {
      acc[i] += bf2f(v0[i]);
      acc[8 + i] += bf2f(v1[i]);
    }
    ls += *(const float*)(pp + 4096 + 2 * q);
  }
  const float inv = __builtin_amdgcn_rcpf(ls);
  short o16[16];
#pragma unroll
  for (int i = 0; i < 16; ++i) o16[i] = f2bf(acc[i] * inv);
  short* yp = y + ((size_t)b * T + qb * 64 + q) * C + h * 64 + dg;
  *(shortx8*)yp = *(shortx8*)&o16[0];
  *(shortx8*)(yp + 8) = *(shortx8*)&o16[8];
}

// ---- fallback single-pass attention (used only if ws too small) ----
__global__ __launch_bounds__(256)
void attention_kernel(const short* __restrict__ qkv, short* __restrict__ y) {
  constexpr int T = 2048, C = 1024, HD = 64, S3 = 3072;
  __shared__ short Ks[64 * 72];
  __shared__ short Vt[64 * 72];
  __shared__ short Ps[4][16 * 72];
  const int qb = blockIdx.x, h = blockIdx.y, b = blockIdx.z;
  const int tid = threadIdx.x, wid = tid >> 6, lane = tid & 63;
  const int quad = lane >> 4, l15 = lane & 15;
  const size_t base = (size_t)b * T * S3;
  const int q0 = qb * 64 + wid * 16;
  const short* Qp = qkv + base + (size_t)(q0 + l15) * S3 + h * HD;
  const shortx8 qf0 = *(const shortx8*)(Qp + quad * 8);
  const shortx8 qf1 = *(const shortx8*)(Qp + 32 + quad * 8);
  floatx4 o[4] = {};
  float lsum[4] = {0.f, 0.f, 0.f, 0.f};
  const float scale2 = 0.03125f * 1.44269504088896f;
  const int skey = tid >> 2, sd = (tid & 3) * 16;
  const int vkp = tid & 31, vdb = tid >> 5;
  for (int kt = 0; kt <= qb; ++kt) {
    const int key0 = kt * 64;
    __syncthreads();
    {
      const short* Kp = qkv + base + (size_t)(key0 + skey) * S3 + C + h * HD + sd;
      shortx8 ka = *(const shortx8*)Kp;
      shortx8 kb = *(const shortx8*)(Kp + 8);
      *(shortx8*)&Ks[skey * 72 + sd] = ka;
      *(shortx8*)&Ks[skey * 72 + sd + 8] = kb;
      const short* Vp = qkv + base + (size_t)(key0 + 2 * vkp) * S3 + 2 * C + h * HD + vdb * 8;
      shortx8 va = *(const shortx8*)Vp;
      shortx8 vb = *(const shortx8*)(Vp + S3);
#pragma unroll
      for (int j = 0; j < 8; ++j) {
        short2 pr = make_short2(va[j], vb[j]);
        *(short2*)&Vt[(vdb * 8 + j) * 72 + 2 * vkp] = pr;
      }
    }
    __syncthreads();
    floatx4 s[4];
#pragma unroll
    for (int nt = 0; nt < 4; ++nt) {
      const short* kb = &Ks[(nt * 16 + l15) * 72 + quad * 8];
      floatx4 a = {};
      a = __builtin_amdgcn_mfma_f32_16x16x32_bf16(qf0, *(const shortx8*)kb, a, 0, 0, 0);
      a = __builtin_amdgcn_mfma_f32_16x16x32_bf16(qf1, *(const shortx8*)(kb + 32), a, 0, 0, 0);
      s[nt] = a;
    }
    short* pw = &Ps[wid][0];
    const bool diag = (kt == qb);
#pragma unroll
    for (int nt = 0; nt < 4; ++nt)
#pragma unroll
      for (int r = 0; r < 4; ++r) {
        float sv = s[nt][r] * scale2;
        if (diag) {
          const int key = key0 + nt * 16 + l15;
          const int q = q0 + quad * 4 + r;
          if (key > q) sv = -INFINITY;
        }
        const float p = __builtin_amdgcn_exp2f(sv);
        lsum[r] += p;
        pw[(quad * 4 + r) * 72 + nt * 16 + l15] = f2bf(p);
      }
    asm volatile("s_waitcnt lgkmcnt(0)" ::: "memory");
#pragma unroll
    for (int kf = 0; kf < 2; ++kf) {
      const shortx8 pa = *(const shortx8*)&Ps[wid][l15 * 72 + kf * 32 + quad * 8];
#pragma unroll
      for (int dt = 0; dt < 4; ++dt) {
        const shortx8 vb = *(const shortx8*)&Vt[(dt * 16 + l15) * 72 + kf * 32 + quad * 8];
        o[dt] = __builtin_amdgcn_mfma_f32_16x16x32_bf16(pa, vb, o[dt], 0, 0, 0);
      }
    }
  }
  float inv[4];
#pragma unroll
  for (int r = 0; r < 4; ++r) {
    float s = lsum[r];
    for (int off = 1; off < 16; off <<= 1) s += __shfl_xor(s, off);
    inv[r] = __builtin_amdgcn_rcpf(s);
  }
#pragma unroll
  for (int dt = 0; dt < 4; ++dt)
#pragma unroll
    for (int r = 0; r < 4; ++r) {
      const int q = q0 + quad * 4 + r;
      y[((size_t)b * T + q) * C + h * HD + dt * 16 + l15] = f2bf(o[dt][r] * inv[r]);
    }
}

extern "C" void kernel_launch(void* const* d_in, const int* in_sizes, int n_in,
                              void* d_out, int out_size, void* d_ws, size_t ws_size,
                              hipStream_t stream) {
  const float* x      = (const float*)d_in[0];
  const float* ln1_w  = (const float*)d_in[1];
  const float* ln1_b  = (const float*)d_in[2];
  const float* qkv_w  = (const float*)d_in[3];
  const float* qkv_b  = (const float*)d_in[4];
  const float* proj_w = (const float*)d_in[5];
  const float* proj_b = (const float*)d_in[6];
  const float* ln2_w  = (const float*)d_in[7];
  const float* ln2_b  = (const float*)d_in[8];
  const float* ff_w1  = (const float*)d_in[9];
  const float* ff_b1  = (const float*)d_in[10];
  const float* ff_w2  = (const float*)d_in[11];
  const float* ff_b2  = (const float*)d_in[12];
  float* out = (float*)d_out;

  char* p = (char*)d_ws;
  short* wT_qkv  = (short*)p; p += (size_t)3072 * 1024 * 2;
  short* wT_proj = (short*)p; p += (size_t)1024 * 1024 * 2;
  short* wT_ff1  = (short*)p; p += (size_t)4096 * 1024 * 2;
  short* wT_ff2  = (short*)p; p += (size_t)1024 * 4096 * 2;
  short* act16   = (short*)p; p += (size_t)8192 * 1024 * 2;  // h -> y -> h2
  short* big     = (short*)p; p += (size_t)8192 * 4096 * 2;  // qkv -> ff act
  float* part    = (float*)p;  // attn partials (43 MB, bf16 O + fp32 lsum)
  const size_t need = (size_t)(p - (char*)d_ws) +
                      (size_t)64 * ATTN_SLOTS * ATTN_SLOT_SH * 2;
  const bool split = (ws_size >= need);

  // weights -> bf16 transposed [N][K]
  transpose_cast<<<dim3(96, 32), 256, 0, stream>>>(qkv_w, wT_qkv, 1024, 3072);
  transpose_cast<<<dim3(32, 32), 256, 0, stream>>>(proj_w, wT_proj, 1024, 1024);
  transpose_cast<<<dim3(128, 32), 256, 0, stream>>>(ff_w1, wT_ff1, 1024, 4096);
  transpose_cast<<<dim3(32, 128), 256, 0, stream>>>(ff_w2, wT_ff2, 4096, 1024);

  // h = LN1(x)
  layernorm_kernel<<<8192, 256, 0, stream>>>(x, ln1_w, ln1_b, act16);
  // qkv = h @ qkv_w + qkv_b           [8192,3072]
  gemm_bt<0, short><<<dim3(24, 64), 256, 0, stream>>>(
      act16, 1024, wT_qkv, 1024, qkv_b, nullptr, big, 8192, 3072, 1024);
  // y = causal_attention(qkv)  — split-K if ws fits, else single-pass
  if (split) {
    attention_chunk<<<dim3(ATTN_SLOTS, 16, 4), 256, 0, stream>>>(big, act16, part);
    attn_reduce<<<dim3(24, 16, 4), 256, 0, stream>>>(part, act16);
  } else {
    attention_kernel<<<dim3(32, 16, 4), 256, 0, stream>>>(big, act16);
  }
  // x2 = x + y @ proj_w + proj_b  -> d_out (fp32)  (BN=64: 1024 blocks, 4/CU)
  gemm_bt_n64<2, float><<<dim3(16, 64), 256, 0, stream>>>(
      act16, 1024, wT_proj, 1024, proj_b, x, out, 8192, 1024, 1024);
  // h2 = LN2(x2)
  layernorm_kernel<<<8192, 256, 0, stream>>>(out, ln2_w, ln2_b, act16);
  // a = relu(h2 @ ff_w1 + ff_b1)      [8192,4096]
  gemm_bt<1, short><<<dim3(32, 64), 256, 0, stream>>>(
      act16, 1024, wT_ff1, 1024, ff_b1, nullptr, big, 8192, 4096, 1024);
  // out = x2 + a @ ff_w2 + ff_b2  (BN=64: 1024 blocks, 4/CU; resid
  // read-before-write, same thread)
  gemm_bt_n64<2, float><<<dim3(16, 64), 256, 0, stream>>>(
      big, 4096, wT_ff2, 4096, ff_b2, out, out, 8192, 1024, 4096);
}

// Round 13
// 511.465 us; speedup vs baseline: 1.0222x; 1.0222x over previous
//
#include <hip/hip_runtime.h>

// Decoder block: x -> LN1 -> QKV GEMM -> causal MHA -> proj(+x) -> LN2 -> FFN(+res)
// B=4 T=2048 C=1024 H=16 hd=64.  All MFMA compute in bf16, fp32 accumulate.

typedef __attribute__((ext_vector_type(8))) short shortx8;   // 8 bf16 (4 VGPR)
typedef __attribute__((ext_vector_type(4))) float floatx4;   // MFMA C/D

__device__ __forceinline__ short f2bf(float f) {
  unsigned u = __builtin_bit_cast(unsigned, f);
  u = (u + 0x7fffu + ((u >> 16) & 1u)) >> 16;   // RNE
  return (short)u;
}
__device__ __forceinline__ float bf2f(short s) {
  return __builtin_bit_cast(float, (unsigned)((unsigned short)s) << 16);
}

// ---- weight transpose + cast: in [K][N] f32 -> out [N][K] bf16 ----
__global__ __launch_bounds__(256)
void transpose_cast(const float* __restrict__ in, short* __restrict__ out,
                    int K, int N) {
  __shared__ float tile[32][33];
  const int n0 = blockIdx.x * 32, k0 = blockIdx.y * 32;
  const int tx = threadIdx.x & 31, ty = threadIdx.x >> 5;  // 32x8
  for (int i = 0; i < 32; i += 8)
    tile[ty + i][tx] = in[(size_t)(k0 + ty + i) * N + n0 + tx];
  __syncthreads();
  for (int i = 0; i < 32; i += 8)
    out[(size_t)(n0 + ty + i) * K + k0 + tx] = f2bf(tile[tx][ty + i]);
}

// ---- layernorm: f32 in -> bf16 out, C=1024, one block (256 thr) per row ----
__global__ __launch_bounds__(256)
void layernorm_kernel(const float* __restrict__ x, const float* __restrict__ w,
                      const float* __restrict__ bta, short* __restrict__ out) {
  const int C = 1024;
  const int row = blockIdx.x;
  const float4 v = ((const float4*)(x + (size_t)row * C))[threadIdx.x];
  float s1 = v.x + v.y + v.z + v.w;
  float s2 = v.x * v.x + v.y * v.y + v.z * v.z + v.w * v.w;
  for (int m = 1; m < 64; m <<= 1) { s1 += __shfl_xor(s1, m); s2 += __shfl_xor(s2, m); }
  __shared__ float r1[4], r2[4];
  const int wid = threadIdx.x >> 6, lane = threadIdx.x & 63;
  if (lane == 0) { r1[wid] = s1; r2[wid] = s2; }
  __syncthreads();
  s1 = r1[0] + r1[1] + r1[2] + r1[3];
  s2 = r2[0] + r2[1] + r2[2] + r2[3];
  const float mean = s1 * (1.0f / C);
  const float var = s2 * (1.0f / C) - mean * mean;
  const float rs = rsqrtf(var + 1e-5f);
  const float4 wv = ((const float4*)w)[threadIdx.x];
  const float4 bv = ((const float4*)bta)[threadIdx.x];
  short4 o;
  o.x = f2bf((v.x - mean) * rs * wv.x + bv.x);
  o.y = f2bf((v.y - mean) * rs * wv.y + bv.y);
  o.z = f2bf((v.z - mean) * rs * wv.z + bv.z);
  o.w = f2bf((v.w - mean) * rs * wv.w + bv.w);
  *(short4*)(out + (size_t)row * C + threadIdx.x * 4) = o;
}

// ---- MFMA GEMM: C = A[M,K]@Bt[N,K]^T + bias (+resid)(+relu)
// 128x128 tile, BK=64 as TWO independent BK=32 sub-tiles (verbatim R6/R11
// source — best verified).  R12: BN=64 variant raised occupancy 20->36% but
// dur got WORSE (92.5 vs 90; +bank conflicts, +A-fetch) -> deleted.  The
// drain here is covered by in-block ILP, not block count.
// FLAGS: bit0=relu, bit1=resid(fp32).  lda/ldb = row strides of A / Bt.
template<int FLAGS, typename OutT>
__global__ __launch_bounds__(256, 4)
void gemm_bt(const short* __restrict__ A, int lda,
             const short* __restrict__ Bt, int ldb,
             const float* __restrict__ bias, const float* __restrict__ resid,
             OutT* __restrict__ C, int M, int N, int K) {
  constexpr bool RELU = (FLAGS & 1) != 0;
  constexpr bool RESID = (FLAGS & 2) != 0;
  __shared__ short As[2][128 * 32];   // [khalf][m][k]
  __shared__ short Bs[2][128 * 32];   // [khalf][n][k]
  int bmi, bni;
  {
    const int nb = gridDim.x, mb = gridDim.y;
    const int g = blockIdx.x + nb * blockIdx.y;
    if ((mb & 7) == 0) {
      const int xcd = g & 7, l = g >> 3;      // 8 XCDs, round-robin dispatch
      bmi = xcd * (mb >> 3) + l / nb;
      bni = l % nb;
    } else { bmi = blockIdx.y; bni = blockIdx.x; }
  }
  const int bm0 = bmi * 128, bn0 = bni * 128;
  const int tid = threadIdx.x, wid = tid >> 6, lane = tid & 63;
  const int quad = lane >> 4, l15 = lane & 15;
  const int wm = wid & 1, wn = wid >> 1;
  const int srow = lane >> 2, scol = (lane & 3) * 8;
  floatx4 acc[4][4] = {};
  for (int k0 = 0; k0 < K; k0 += 64) {
    for (int i = 0; i < 2; ++i) {
      const int r0 = (wid * 2 + i) * 16;
      const short* ga = A + (size_t)(bm0 + r0 + srow) * lda + k0 + scol;
      const short* gb = Bt + (size_t)(bn0 + r0 + srow) * ldb + k0 + scol;
      __builtin_amdgcn_global_load_lds(
          (const __attribute__((address_space(1))) void*)ga,
          (__attribute__((address_space(3))) void*)&As[0][r0 * 32], 16, 0, 0);
      __builtin_amdgcn_global_load_lds(
          (const __attribute__((address_space(1))) void*)(ga + 32),
          (__attribute__((address_space(3))) void*)&As[1][r0 * 32], 16, 0, 0);
      __builtin_amdgcn_global_load_lds(
          (const __attribute__((address_space(1))) void*)gb,
          (__attribute__((address_space(3))) void*)&Bs[0][r0 * 32], 16, 0, 0);
      __builtin_amdgcn_global_load_lds(
          (const __attribute__((address_space(1))) void*)(gb + 32),
          (__attribute__((address_space(3))) void*)&Bs[1][r0 * 32], 16, 0, 0);
    }
    asm volatile("s_waitcnt vmcnt(0)" ::: "memory");
    __syncthreads();
    // half 0
    {
      shortx8 af[4], bfr[4];
#pragma unroll
      for (int i = 0; i < 4; ++i)
        af[i] = *(const shortx8*)&As[0][(wm * 64 + i * 16 + l15) * 32 + quad * 8];
#pragma unroll
      for (int j = 0; j < 4; ++j)
        bfr[j] = *(const shortx8*)&Bs[0][(wn * 64 + j * 16 + l15) * 32 + quad * 8];
#pragma unroll
      for (int i = 0; i < 4; ++i)
#pragma unroll
        for (int j = 0; j < 4; ++j)
          acc[i][j] = __builtin_amdgcn_mfma_f32_16x16x32_bf16(af[i], bfr[j], acc[i][j], 0, 0, 0);
    }
    // half 1
    {
      shortx8 af[4], bfr[4];
#pragma unroll
      for (int i = 0; i < 4; ++i)
        af[i] = *(const shortx8*)&As[1][(wm * 64 + i * 16 + l15) * 32 + quad * 8];
#pragma unroll
      for (int j = 0; j < 4; ++j)
        bfr[j] = *(const shortx8*)&Bs[1][(wn * 64 + j * 16 + l15) * 32 + quad * 8];
#pragma unroll
      for (int i = 0; i < 4; ++i)
#pragma unroll
        for (int j = 0; j < 4; ++j)
          acc[i][j] = __builtin_amdgcn_mfma_f32_16x16x32_bf16(af[i], bfr[j], acc[i][j], 0, 0, 0);
    }
    __syncthreads();
  }
  // epilogue: D row = (lane>>4)*4 + reg, col = lane&15 (m89/m91-verified)
#pragma unroll
  for (int i = 0; i < 4; ++i) {
    const int row = bm0 + wm * 64 + i * 16 + quad * 4;
#pragma unroll
    for (int j = 0; j < 4; ++j) {
      const int col = bn0 + wn * 64 + j * 16 + l15;
      const float bb = bias[col];
#pragma unroll
      for (int r = 0; r < 4; ++r) {
        float v = acc[i][j][r] + bb;
        if (RELU) v = fmaxf(v, 0.0f);
        if (RESID) v += resid[(size_t)(row + r) * N + col];
        if constexpr (sizeof(OutT) == 2)
          C[(size_t)(row + r) * N + col] = f2bf(v);
        else
          C[(size_t)(row + r) * N + col] = v;
      }
    }
  }
}

// ================= split-K flash attention =================
// Static-max softmax (scores = q.k/32, tiny; fp32 exp2 has huge headroom) makes
// chunk partials ADDITIVE: O_unnorm = sum P.V, lsum = sum p.
//
// R13: 8-WAVE QBLK=128 — 512 threads, each wave owns ONE 16-row strip
// (per-tile per-wave compute path is verbatim R6; R4's failure was SERIAL
// strips in one wave, this has none).  128 q-rows share each staged K/V tile:
// barrier-epochs per (h,b) halve (528->272) and K/V HBM re-reads halve.
// Staging split by wave-group, REUSING the verified index math: waves 0-3
// stage V (vkp/vdb pattern), waves 4-7 stage K (skey/sd pattern).
// Causality per wave: qbw = 2*qb0 + (wid>>2); fully-masked tiles skipped by
// a wave-uniform continue placed AFTER both barriers.
// R3: P k-PERMUTED for v_cvt_pk_bf16_f32; Vt permuted identically (exact).
// R6: raw v_exp_f32, wave-uniform diag split, v_rcp_f32.
// R11: bf16 O partials (lsum fp32).
// Slots: tiles per qb0 = 2*qb0+2, chunks of 8 tiles.
#define ATTN_SLOTS 40           // sum over qb0 of ceil((2qb0+2)/8)
#define ATTN_SLOT_SH 8448       // shorts: 128*64 bf16 O + 128 fp32 lsum

__global__ __launch_bounds__(512)
void attention_chunk(const short* __restrict__ qkv, short* __restrict__ y,
                     float* __restrict__ part) {
  constexpr int T = 2048, C = 1024, HD = 64, S3 = 3072;
  __shared__ short Ks[64 * 72];      // [key][d], pad 72
  __shared__ short Vt[64 * 72];      // [d][k'], permuted keys, pad 72
  __shared__ short Ps[8][16 * 72];   // per-wave P: [q][k'], permuted
  const int x = blockIdx.x, h = blockIdx.y, b = blockIdx.z;
  int qb0, ch;
  if (x < 4)       { qb0 = x;                    ch = 0; }
  else if (x < 12) { qb0 = 4 + ((x - 4) >> 1);   ch = (x - 4) & 1; }
  else if (x < 24) { qb0 = 8 + (x - 12) / 3;     ch = (x - 12) % 3; }
  else             { qb0 = 12 + ((x - 24) >> 2); ch = (x - 24) & 3; }
  const int kt0 = ch * 8;
  const int kt1 = min(kt0 + 8, 2 * qb0 + 2);
  const int tid = threadIdx.x, wid = tid >> 6, lane = tid & 63;
  const int quad = lane >> 4, l15 = lane & 15;
  const int qbw = 2 * qb0 + (wid >> 2);   // this wave's diag tile index
  const size_t base = (size_t)b * T * S3;
  const int q0 = qb0 * 128 + wid * 16;
  // Q A-frags: A[m=lane&15][k=quad*8+j]
  const short* Qp = qkv + base + (size_t)(q0 + l15) * S3 + h * HD;
  const shortx8 qf0 = *(const shortx8*)(Qp + quad * 8);
  const shortx8 qf1 = *(const shortx8*)(Qp + 32 + quad * 8);
  floatx4 o[4] = {};
  float lsum[4] = {0.f, 0.f, 0.f, 0.f};
  const float scale2 = 0.03125f * 1.44269504088896f;  // 1/sqrt(C) * log2(e)
  // staging roles: tid<256 stages V (R6 vkp/vdb pattern), tid>=256 stages K
  const int t2 = tid & 255;
  const int skey = t2 >> 2, sd = (t2 & 3) * 16;    // K staging (waves 4-7)
  const int vkp = tid & 31, vdb = (tid >> 5) & 7;  // V staging (waves 0-3)
  const int vkE = (vkp >> 4) * 32 + (vkp & 15);    // even-k' source key row
  const short* Kbase = qkv + base + C + h * HD;
  const short* Vbase = qkv + base + 2 * C + h * HD;
  // register prefetch of tile kt0 (role-split)
  shortx8 pk0, pk1, pv0, pv1;
  if (tid < 256) {
    const short* Vp = Vbase + (size_t)(kt0 * 64 + vkE) * S3 + vdb * 8;
    pv0 = *(const shortx8*)Vp;            // key c   -> k' even (lo)
    pv1 = *(const shortx8*)(Vp + 16 * S3);// key c+16 -> k' odd (hi)
  } else {
    const short* Kp = Kbase + (size_t)(kt0 * 64 + skey) * S3 + sd;
    pk0 = *(const shortx8*)Kp;
    pk1 = *(const shortx8*)(Kp + 8);
  }
  for (int kt = kt0; kt < kt1; ++kt) {
    const int key0 = kt * 64;
    __syncthreads();
    if (tid < 256) {
#pragma unroll
      for (int j = 0; j < 8; ++j) {
        short2 pr = make_short2(pv0[j], pv1[j]);
        *(short2*)&Vt[(vdb * 8 + j) * 72 + 2 * vkp] = pr;
      }
    } else {
      *(shortx8*)&Ks[skey * 72 + sd] = pk0;
      *(shortx8*)&Ks[skey * 72 + sd + 8] = pk1;
    }
    __syncthreads();
    if (kt + 1 < kt1) {  // prefetch next tile (role-split)
      const int kn = key0 + 64;
      if (tid < 256) {
        const short* Vp = Vbase + (size_t)(kn + vkE) * S3 + vdb * 8;
        pv0 = *(const shortx8*)Vp;
        pv1 = *(const shortx8*)(Vp + 16 * S3);
      } else {
        const short* Kp = Kbase + (size_t)(kn + skey) * S3 + sd;
        pk0 = *(const shortx8*)Kp;
        pk1 = *(const shortx8*)(Kp + 8);
      }
    }
    if (kt > qbw) continue;   // wave-uniform: fully-masked tile (after barriers)
    floatx4 s[4];
#pragma unroll
    for (int nt = 0; nt < 4; ++nt) {
      const short* kb = &Ks[(nt * 16 + l15) * 72 + quad * 8];
      floatx4 a = {};
      a = __builtin_amdgcn_mfma_f32_16x16x32_bf16(qf0, *(const shortx8*)kb, a, 0, 0, 0);
      a = __builtin_amdgcn_mfma_f32_16x16x32_bf16(qf1, *(const shortx8*)(kb + 32), a, 0, 0, 0);
      s[nt] = a;
    }
    short* pw = &Ps[wid][0];
    if (kt != qbw) {  // fast path: no causal mask in this tile (wave-uniform)
#pragma unroll
      for (int r = 0; r < 4; ++r) {
        const float p0 = __builtin_amdgcn_exp2f(s[0][r] * scale2);
        const float p1 = __builtin_amdgcn_exp2f(s[1][r] * scale2);
        const float p2 = __builtin_amdgcn_exp2f(s[2][r] * scale2);
        const float p3 = __builtin_amdgcn_exp2f(s[3][r] * scale2);
        lsum[r] += (p0 + p1) + (p2 + p3);
        unsigned w0, w1;
        asm("v_cvt_pk_bf16_f32 %0, %1, %2" : "=v"(w0) : "v"(p0), "v"(p1));
        asm("v_cvt_pk_bf16_f32 %0, %1, %2" : "=v"(w1) : "v"(p2), "v"(p3));
        unsigned* prow = (unsigned*)&pw[(quad * 4 + r) * 72];
        prow[l15] = w0;        // k' = 2*l15, 2*l15+1        (cols l15, l15+16)
        prow[16 + l15] = w1;   // k' = 32+2*l15, 32+2*l15+1  (cols l15+32, l15+48)
      }
    } else {          // diag tile: mask key > q
#pragma unroll
      for (int r = 0; r < 4; ++r) {
        const int q = q0 + quad * 4 + r;
        float pr[4];
#pragma unroll
        for (int nt = 0; nt < 4; ++nt) {
          float sv = s[nt][r] * scale2;
          if (key0 + nt * 16 + l15 > q) sv = -INFINITY;
          pr[nt] = __builtin_amdgcn_exp2f(sv);  // v_exp_f32(-inf)=0
        }
        lsum[r] += (pr[0] + pr[1]) + (pr[2] + pr[3]);
        unsigned w0, w1;
        asm("v_cvt_pk_bf16_f32 %0, %1, %2" : "=v"(w0) : "v"(pr[0]), "v"(pr[1]));
        asm("v_cvt_pk_bf16_f32 %0, %1, %2" : "=v"(w1) : "v"(pr[2]), "v"(pr[3]));
        unsigned* prow = (unsigned*)&pw[(quad * 4 + r) * 72];
        prow[l15] = w0;
        prow[16 + l15] = w1;
      }
    }
    asm volatile("s_waitcnt lgkmcnt(0)" ::: "memory");
#pragma unroll
    for (int kf = 0; kf < 2; ++kf) {
      const shortx8 pa = *(const shortx8*)&Ps[wid][l15 * 72 + kf * 32 + quad * 8];
#pragma unroll
      for (int dt = 0; dt < 4; ++dt) {
        const shortx8 vb = *(const shortx8*)&Vt[(dt * 16 + l15) * 72 + kf * 32 + quad * 8];
        o[dt] = __builtin_amdgcn_mfma_f32_16x16x32_bf16(pa, vb, o[dt], 0, 0, 0);
      }
    }
  }
  // reduce lsum over the 16 lanes of each quad group
  float ls[4];
#pragma unroll
  for (int r = 0; r < 4; ++r) {
    float s = lsum[r];
    for (int off = 1; off < 16; off <<= 1) s += __shfl_xor(s, off);
    ls[r] = s;
  }
  if (x < 4) {  // single chunk -> final output
    float inv[4];
#pragma unroll
    for (int r = 0; r < 4; ++r) inv[r] = __builtin_amdgcn_rcpf(ls[r]);
#pragma unroll
    for (int dt = 0; dt < 4; ++dt)
#pragma unroll
      for (int r = 0; r < 4; ++r) {
        const int q = q0 + quad * 4 + r;
        y[((size_t)b * T + q) * C + h * HD + dt * 16 + l15] =
            f2bf(o[dt][r] * inv[r]);
      }
  } else {      // bf16 O partials [128q x 64d] + fp32 lsum [128]
    short* pp = (short*)part +
                ((size_t)(b * 16 + h) * ATTN_SLOTS + x) * ATTN_SLOT_SH;
    float* pl = (float*)(pp + 8192);
    const int rw = wid * 16;
#pragma unroll
    for (int dt = 0; dt < 4; ++dt)
#pragma unroll
      for (int r = 0; r < 4; ++r)
        pp[(rw + quad * 4 + r) * 64 + dt * 16 + l15] = f2bf(o[dt][r]);
    if (l15 == 0)
#pragma unroll
      for (int r = 0; r < 4; ++r)
        pl[rw + quad * 4 + r] = ls[r];
  }
}

__global__ __launch_bounds__(256)
void attn_reduce(const float* __restrict__ part, short* __restrict__ y) {
  constexpr int T = 2048, C = 1024;
  const int qb0 = 4 + blockIdx.x, h = blockIdx.y, b = blockIdx.z;
  const int c = qb0 / 4 + 1;  // 2..4 chunks
  int slot0;
  if (qb0 < 8)       slot0 = 4 + 2 * (qb0 - 4);
  else if (qb0 < 12) slot0 = 12 + 3 * (qb0 - 8);
  else               slot0 = 24 + 4 * (qb0 - 12);
  const short* rb = (const short*)part +
                    ((size_t)(b * 16 + h) * ATTN_SLOTS + slot0) * ATTN_SLOT_SH;
  const int t = threadIdx.x;
  const int q = t >> 1, dg = (t & 1) * 32;   // 128 rows x 2 half-rows
  float acc[32] = {};
  float ls = 0.f;
  for (int ci = 0; ci < c; ++ci) {
    const short* pp = rb + (size_t)ci * ATTN_SLOT_SH;
#pragma unroll
    for (int v = 0; v < 4; ++v) {
      const shortx8 w = *(const shortx8*)(pp + q * 64 + dg + 8 * v);
#pragma unroll
      for (int i = 0; i < 8; ++i) acc[8 * v + i] += bf2f(w[i]);
    }
    ls += ((const float*)(pp + 8192))[q];
  }
  const float inv = __builtin_amdgcn_rcpf(ls);
  short o16[32];
#pragma unroll
  for (int i = 0; i < 32; ++i) o16[i] = f2bf(acc[i] * inv);
  short* yp = y + ((size_t)b * T + qb0 * 128 + q) * C + h * 64 + dg;
#pragma unroll
  for (int v = 0; v < 4; ++v)
    *(shortx8*)(yp + 8 * v) = *(shortx8*)&o16[8 * v];
}

// ---- fallback single-pass attention (used only if ws too small) ----
__global__ __launch_bounds__(256)
void attention_kernel(const short* __restrict__ qkv, short* __restrict__ y) {
  constexpr int T = 2048, C = 1024, HD = 64, S3 = 3072;
  __shared__ short Ks[64 * 72];
  __shared__ short Vt[64 * 72];
  __shared__ short Ps[4][16 * 72];
  const int qb = blockIdx.x, h = blockIdx.y, b = blockIdx.z;
  const int tid = threadIdx.x, wid = tid >> 6, lane = tid & 63;
  const int quad = lane >> 4, l15 = lane & 15;
  const size_t base = (size_t)b * T * S3;
  const int q0 = qb * 64 + wid * 16;
  const short* Qp = qkv + base + (size_t)(q0 + l15) * S3 + h * HD;
  const shortx8 qf0 = *(const shortx8*)(Qp + quad * 8);
  const shortx8 qf1 = *(const shortx8*)(Qp + 32 + quad * 8);
  floatx4 o[4] = {};
  float lsum[4] = {0.f, 0.f, 0.f, 0.f};
  const float scale2 = 0.03125f * 1.44269504088896f;
  const int skey = tid >> 2, sd = (tid & 3) * 16;
  const int vkp = tid & 31, vdb = tid >> 5;
  for (int kt = 0; kt <= qb; ++kt) {
    const int key0 = kt * 64;
    __syncthreads();
    {
      const short* Kp = qkv + base + (size_t)(key0 + skey) * S3 + C + h * HD + sd;
      shortx8 ka = *(const shortx8*)Kp;
      shortx8 kb = *(const shortx8*)(Kp + 8);
      *(shortx8*)&Ks[skey * 72 + sd] = ka;
      *(shortx8*)&Ks[skey * 72 + sd + 8] = kb;
      const short* Vp = qkv + base + (size_t)(key0 + 2 * vkp) * S3 + 2 * C + h * HD + vdb * 8;
      shortx8 va = *(const shortx8*)Vp;
      shortx8 vb = *(const shortx8*)(Vp + S3);
#pragma unroll
      for (int j = 0; j < 8; ++j) {
        short2 pr = make_short2(va[j], vb[j]);
        *(short2*)&Vt[(vdb * 8 + j) * 72 + 2 * vkp] = pr;
      }
    }
    __syncthreads();
    floatx4 s[4];
#pragma unroll
    for (int nt = 0; nt < 4; ++nt) {
      const short* kb = &Ks[(nt * 16 + l15) * 72 + quad * 8];
      floatx4 a = {};
      a = __builtin_amdgcn_mfma_f32_16x16x32_bf16(qf0, *(const shortx8*)kb, a, 0, 0, 0);
      a = __builtin_amdgcn_mfma_f32_16x16x32_bf16(qf1, *(const shortx8*)(kb + 32), a, 0, 0, 0);
      s[nt] = a;
    }
    short* pw = &Ps[wid][0];
    const bool diag = (kt == qb);
#pragma unroll
    for (int nt = 0; nt < 4; ++nt)
#pragma unroll
      for (int r = 0; r < 4; ++r) {
        float sv = s[nt][r] * scale2;
        if (diag) {
          const int key = key0 + nt * 16 + l15;
          const int q = q0 + quad * 4 + r;
          if (key > q) sv = -INFINITY;
        }
        const float p = __builtin_amdgcn_exp2f(sv);
        lsum[r] += p;
        pw[(quad * 4 + r) * 72 + nt * 16 + l15] = f2bf(p);
      }
    asm volatile("s_waitcnt lgkmcnt(0)" ::: "memory");
#pragma unroll
    for (int kf = 0; kf < 2; ++kf) {
      const shortx8 pa = *(const shortx8*)&Ps[wid][l15 * 72 + kf * 32 + quad * 8];
#pragma unroll
      for (int dt = 0; dt < 4; ++dt) {
        const shortx8 vb = *(const shortx8*)&Vt[(dt * 16 + l15) * 72 + kf * 32 + quad * 8];
        o[dt] = __builtin_amdgcn_mfma_f32_16x16x32_bf16(pa, vb, o[dt], 0, 0, 0);
      }
    }
  }
  float inv[4];
#pragma unroll
  for (int r = 0; r < 4; ++r) {
    float s = lsum[r];
    for (int off = 1; off < 16; off <<= 1) s += __shfl_xor(s, off);
    inv[r] = __builtin_amdgcn_rcpf(s);
  }
#pragma unroll
  for (int dt = 0; dt < 4; ++dt)
#pragma unroll
    for (int r = 0; r < 4; ++r) {
      const int q = q0 + quad * 4 + r;
      y[((size_t)b * T + q) * C + h * HD + dt * 16 + l15] = f2bf(o[dt][r] * inv[r]);
    }
}

extern "C" void kernel_launch(void* const* d_in, const int* in_sizes, int n_in,
                              void* d_out, int out_size, void* d_ws, size_t ws_size,
                              hipStream_t stream) {
  const float* x      = (const float*)d_in[0];
  const float* ln1_w  = (const float*)d_in[1];
  const float* ln1_b  = (const float*)d_in[2];
  const float* qkv_w  = (const float*)d_in[3];
  const float* qkv_b  = (const float*)d_in[4];
  const float* proj_w = (const float*)d_in[5];
  const float* proj_b = (const float*)d_in[6];
  const float* ln2_w  = (const float*)d_in[7];
  const float* ln2_b  = (const float*)d_in[8];
  const float* ff_w1  = (const float*)d_in[9];
  const float* ff_b1  = (const float*)d_in[10];
  const float* ff_w2  = (const float*)d_in[11];
  const float* ff_b2  = (const float*)d_in[12];
  float* out = (float*)d_out;

  char* p = (char*)d_ws;
  short* wT_qkv  = (short*)p; p += (size_t)3072 * 1024 * 2;
  short* wT_proj = (short*)p; p += (size_t)1024 * 1024 * 2;
  short* wT_ff1  = (short*)p; p += (size_t)4096 * 1024 * 2;
  short* wT_ff2  = (short*)p; p += (size_t)1024 * 4096 * 2;
  short* act16   = (short*)p; p += (size_t)8192 * 1024 * 2;  // h -> y -> h2
  short* big     = (short*)p; p += (size_t)8192 * 4096 * 2;  // qkv -> ff act
  float* part    = (float*)p;  // attn partials (43 MB, bf16 O + fp32 lsum)
  const size_t need = (size_t)(p - (char*)d_ws) +
                      (size_t)64 * ATTN_SLOTS * ATTN_SLOT_SH * 2;
  const bool split = (ws_size >= need);

  // weights -> bf16 transposed [N][K]
  transpose_cast<<<dim3(96, 32), 256, 0, stream>>>(qkv_w, wT_qkv, 1024, 3072);
  transpose_cast<<<dim3(32, 32), 256, 0, stream>>>(proj_w, wT_proj, 1024, 1024);
  transpose_cast<<<dim3(128, 32), 256, 0, stream>>>(ff_w1, wT_ff1, 1024, 4096);
  transpose_cast<<<dim3(32, 128), 256, 0, stream>>>(ff_w2, wT_ff2, 4096, 1024);

  // h = LN1(x)
  layernorm_kernel<<<8192, 256, 0, stream>>>(x, ln1_w, ln1_b, act16);
  // qkv = h @ qkv_w + qkv_b           [8192,3072]
  gemm_bt<0, short><<<dim3(24, 64), 256, 0, stream>>>(
      act16, 1024, wT_qkv, 1024, qkv_b, nullptr, big, 8192, 3072, 1024);
  // y = causal_attention(qkv)  — split-K if ws fits, else single-pass
  if (split) {
    attention_chunk<<<dim3(ATTN_SLOTS, 16, 4), 512, 0, stream>>>(big, act16, part);
    attn_reduce<<<dim3(12, 16, 4), 256, 0, stream>>>(part, act16);
  } else {
    attention_kernel<<<dim3(32, 16, 4), 256, 0, stream>>>(big, act16);
  }
  // x2 = x + y @ proj_w + proj_b  -> d_out (fp32)
  gemm_bt<2, float><<<dim3(8, 64), 256, 0, stream>>>(
      act16, 1024, wT_proj, 1024, proj_b, x, out, 8192, 1024, 1024);
  // h2 = LN2(x2)
  layernorm_kernel<<<8192, 256, 0, stream>>>(out, ln2_w, ln2_b, act16);
  // a = relu(h2 @ ff_w1 + ff_b1)      [8192,4096]
  gemm_bt<1, short><<<dim3(32, 64), 256, 0, stream>>>(
      act16, 1024, wT_ff1, 1024, ff_b1, nullptr, big, 8192, 4096, 1024);
  // out = x2 + a @ ff_w2 + ff_b2  (resid read-before-write, same thread)
  gemm_bt<2, float><<<dim3(8, 64), 256, 0, stream>>>(
      big, 4096, wT_ff2, 4096, ff_b2, out, out, 8192, 1024, 4096);
}

// Round 14
// 482.870 us; speedup vs baseline: 1.0827x; 1.0592x over previous
//
#include <hip/hip_runtime.h>

// Decoder block: x -> LN1 -> QKV GEMM -> causal MHA -> proj(+x) -> LN2 -> FFN(+res)
// B=4 T=2048 C=1024 H=16 hd=64.  All MFMA compute in bf16, fp32 accumulate.

typedef __attribute__((ext_vector_type(8))) short shortx8;   // 8 bf16 (4 VGPR)
typedef __attribute__((ext_vector_type(4))) float floatx4;   // MFMA C/D

__device__ __forceinline__ short f2bf(float f) {
  unsigned u = __builtin_bit_cast(unsigned, f);
  u = (u + 0x7fffu + ((u >> 16) & 1u)) >> 16;   // RNE
  return (short)u;
}
__device__ __forceinline__ float bf2f(short s) {
  return __builtin_bit_cast(float, (unsigned)((unsigned short)s) << 16);
}

// ---- weight transpose + cast: in [K][N] f32 -> out [N][K] bf16 ----
__global__ __launch_bounds__(256)
void transpose_cast(const float* __restrict__ in, short* __restrict__ out,
                    int K, int N) {
  __shared__ float tile[32][33];
  const int n0 = blockIdx.x * 32, k0 = blockIdx.y * 32;
  const int tx = threadIdx.x & 31, ty = threadIdx.x >> 5;  // 32x8
  for (int i = 0; i < 32; i += 8)
    tile[ty + i][tx] = in[(size_t)(k0 + ty + i) * N + n0 + tx];
  __syncthreads();
  for (int i = 0; i < 32; i += 8)
    out[(size_t)(n0 + ty + i) * K + k0 + tx] = f2bf(tile[tx][ty + i]);
}

// ---- layernorm: f32 in -> bf16 out, C=1024, one block (256 thr) per row ----
__global__ __launch_bounds__(256)
void layernorm_kernel(const float* __restrict__ x, const float* __restrict__ w,
                      const float* __restrict__ bta, short* __restrict__ out) {
  const int C = 1024;
  const int row = blockIdx.x;
  const float4 v = ((const float4*)(x + (size_t)row * C))[threadIdx.x];
  float s1 = v.x + v.y + v.z + v.w;
  float s2 = v.x * v.x + v.y * v.y + v.z * v.z + v.w * v.w;
  for (int m = 1; m < 64; m <<= 1) { s1 += __shfl_xor(s1, m); s2 += __shfl_xor(s2, m); }
  __shared__ float r1[4], r2[4];
  const int wid = threadIdx.x >> 6, lane = threadIdx.x & 63;
  if (lane == 0) { r1[wid] = s1; r2[wid] = s2; }
  __syncthreads();
  s1 = r1[0] + r1[1] + r1[2] + r1[3];
  s2 = r2[0] + r2[1] + r2[2] + r2[3];
  const float mean = s1 * (1.0f / C);
  const float var = s2 * (1.0f / C) - mean * mean;
  const float rs = rsqrtf(var + 1e-5f);
  const float4 wv = ((const float4*)w)[threadIdx.x];
  const float4 bv = ((const float4*)bta)[threadIdx.x];
  short4 o;
  o.x = f2bf((v.x - mean) * rs * wv.x + bv.x);
  o.y = f2bf((v.y - mean) * rs * wv.y + bv.y);
  o.z = f2bf((v.z - mean) * rs * wv.z + bv.z);
  o.w = f2bf((v.w - mean) * rs * wv.w + bv.w);
  *(short4*)(out + (size_t)row * C + threadIdx.x * 4) = o;
}

// ---- MFMA GEMM: C = A[M,K]@Bt[N,K]^T + bias (+resid)(+relu)
// 128x128 tile, BK=64 as TWO independent BK=32 sub-tiles (hand-written,
// verbatim R6 — best verified).  Used by qkv/proj/ff1.
// R12: BN=64 variant regressed (occupancy up, bank conflicts up) -> deleted.
// R13 noise model: totals vary ±15us across sessions; per-dispatch counters
// are the decision signal.  FLAGS: bit0=relu, bit1=resid(fp32).
template<int FLAGS, typename OutT>
__global__ __launch_bounds__(256, 4)
void gemm_bt(const short* __restrict__ A, int lda,
             const short* __restrict__ Bt, int ldb,
             const float* __restrict__ bias, const float* __restrict__ resid,
             OutT* __restrict__ C, int M, int N, int K) {
  constexpr bool RELU = (FLAGS & 1) != 0;
  constexpr bool RESID = (FLAGS & 2) != 0;
  __shared__ short As[2][128 * 32];   // [khalf][m][k]
  __shared__ short Bs[2][128 * 32];   // [khalf][n][k]
  int bmi, bni;
  {
    const int nb = gridDim.x, mb = gridDim.y;
    const int g = blockIdx.x + nb * blockIdx.y;
    if ((mb & 7) == 0) {
      const int xcd = g & 7, l = g >> 3;      // 8 XCDs, round-robin dispatch
      bmi = xcd * (mb >> 3) + l / nb;
      bni = l % nb;
    } else { bmi = blockIdx.y; bni = blockIdx.x; }
  }
  const int bm0 = bmi * 128, bn0 = bni * 128;
  const int tid = threadIdx.x, wid = tid >> 6, lane = tid & 63;
  const int quad = lane >> 4, l15 = lane & 15;
  const int wm = wid & 1, wn = wid >> 1;
  const int srow = lane >> 2, scol = (lane & 3) * 8;
  floatx4 acc[4][4] = {};
  for (int k0 = 0; k0 < K; k0 += 64) {
    for (int i = 0; i < 2; ++i) {
      const int r0 = (wid * 2 + i) * 16;
      const short* ga = A + (size_t)(bm0 + r0 + srow) * lda + k0 + scol;
      const short* gb = Bt + (size_t)(bn0 + r0 + srow) * ldb + k0 + scol;
      __builtin_amdgcn_global_load_lds(
          (const __attribute__((address_space(1))) void*)ga,
          (__attribute__((address_space(3))) void*)&As[0][r0 * 32], 16, 0, 0);
      __builtin_amdgcn_global_load_lds(
          (const __attribute__((address_space(1))) void*)(ga + 32),
          (__attribute__((address_space(3))) void*)&As[1][r0 * 32], 16, 0, 0);
      __builtin_amdgcn_global_load_lds(
          (const __attribute__((address_space(1))) void*)gb,
          (__attribute__((address_space(3))) void*)&Bs[0][r0 * 32], 16, 0, 0);
      __builtin_amdgcn_global_load_lds(
          (const __attribute__((address_space(1))) void*)(gb + 32),
          (__attribute__((address_space(3))) void*)&Bs[1][r0 * 32], 16, 0, 0);
    }
    asm volatile("s_waitcnt vmcnt(0)" ::: "memory");
    __syncthreads();
    // half 0
    {
      shortx8 af[4], bfr[4];
#pragma unroll
      for (int i = 0; i < 4; ++i)
        af[i] = *(const shortx8*)&As[0][(wm * 64 + i * 16 + l15) * 32 + quad * 8];
#pragma unroll
      for (int j = 0; j < 4; ++j)
        bfr[j] = *(const shortx8*)&Bs[0][(wn * 64 + j * 16 + l15) * 32 + quad * 8];
#pragma unroll
      for (int i = 0; i < 4; ++i)
#pragma unroll
        for (int j = 0; j < 4; ++j)
          acc[i][j] = __builtin_amdgcn_mfma_f32_16x16x32_bf16(af[i], bfr[j], acc[i][j], 0, 0, 0);
    }
    // half 1
    {
      shortx8 af[4], bfr[4];
#pragma unroll
      for (int i = 0; i < 4; ++i)
        af[i] = *(const shortx8*)&As[1][(wm * 64 + i * 16 + l15) * 32 + quad * 8];
#pragma unroll
      for (int j = 0; j < 4; ++j)
        bfr[j] = *(const shortx8*)&Bs[1][(wn * 64 + j * 16 + l15) * 32 + quad * 8];
#pragma unroll
      for (int i = 0; i < 4; ++i)
#pragma unroll
        for (int j = 0; j < 4; ++j)
          acc[i][j] = __builtin_amdgcn_mfma_f32_16x16x32_bf16(af[i], bfr[j], acc[i][j], 0, 0, 0);
    }
    __syncthreads();
  }
  // epilogue: D row = (lane>>4)*4 + reg, col = lane&15 (m89/m91-verified)
#pragma unroll
  for (int i = 0; i < 4; ++i) {
    const int row = bm0 + wm * 64 + i * 16 + quad * 4;
#pragma unroll
    for (int j = 0; j < 4; ++j) {
      const int col = bn0 + wn * 64 + j * 16 + l15;
      const float bb = bias[col];
#pragma unroll
      for (int r = 0; r < 4; ++r) {
        float v = acc[i][j][r] + bb;
        if (RELU) v = fmaxf(v, 0.0f);
        if (RESID) v += resid[(size_t)(row + r) * N + col];
        if constexpr (sizeof(OutT) == 2)
          C[(size_t)(row + r) * N + col] = f2bf(v);
        else
          C[(size_t)(row + r) * N + col] = v;
      }
    }
  }
}

// ---- BK=128 GEMM (FOUR hand-unrolled BK=32 sub-tiles) for ff2 ONLY ----
// ff2 (K=4096, grid 512 = 2 blocks/CU, grid-capped): 64KB LDS is free, and
// 16 K-iters (vs 64) quarter the vmcnt(0)+barrier drains.  Per-dispatch
// evidence from R7/R10: KH=4-ff2 dropped ff2 out of the top-5 (<86.6us vs
// 90-91.6 at BK=64) both times; the "total regressions" that killed it are
// now attributed to ±15us session noise (R13 post-mortem).  Hand-written
// (not a KH template) to match the proven gemm_bt style.
template<int FLAGS, typename OutT>
__global__ __launch_bounds__(256, 4)
void gemm_bt_k128(const short* __restrict__ A, int lda,
                  const short* __restrict__ Bt, int ldb,
                  const float* __restrict__ bias, const float* __restrict__ resid,
                  OutT* __restrict__ C, int M, int N, int K) {
  constexpr bool RELU = (FLAGS & 1) != 0;
  constexpr bool RESID = (FLAGS & 2) != 0;
  __shared__ short As[4][128 * 32];   // [khalf][m][k]
  __shared__ short Bs[4][128 * 32];   // [khalf][n][k]
  int bmi, bni;
  {
    const int nb = gridDim.x, mb = gridDim.y;
    const int g = blockIdx.x + nb * blockIdx.y;
    if ((mb & 7) == 0) {
      const int xcd = g & 7, l = g >> 3;
      bmi = xcd * (mb >> 3) + l / nb;
      bni = l % nb;
    } else { bmi = blockIdx.y; bni = blockIdx.x; }
  }
  const int bm0 = bmi * 128, bn0 = bni * 128;
  const int tid = threadIdx.x, wid = tid >> 6, lane = tid & 63;
  const int quad = lane >> 4, l15 = lane & 15;
  const int wm = wid & 1, wn = wid >> 1;
  const int srow = lane >> 2, scol = (lane & 3) * 8;
  floatx4 acc[4][4] = {};
  for (int k0 = 0; k0 < K; k0 += 128) {
    for (int i = 0; i < 2; ++i) {
      const int r0 = (wid * 2 + i) * 16;
      const short* ga = A + (size_t)(bm0 + r0 + srow) * lda + k0 + scol;
      const short* gb = Bt + (size_t)(bn0 + r0 + srow) * ldb + k0 + scol;
      __builtin_amdgcn_global_load_lds(
          (const __attribute__((address_space(1))) void*)ga,
          (__attribute__((address_space(3))) void*)&As[0][r0 * 32], 16, 0, 0);
      __builtin_amdgcn_global_load_lds(
          (const __attribute__((address_space(1))) void*)(ga + 32),
          (__attribute__((address_space(3))) void*)&As[1][r0 * 32], 16, 0, 0);
      __builtin_amdgcn_global_load_lds(
          (const __attribute__((address_space(1))) void*)(ga + 64),
          (__attribute__((address_space(3))) void*)&As[2][r0 * 32], 16, 0, 0);
      __builtin_amdgcn_global_load_lds(
          (const __attribute__((address_space(1))) void*)(ga + 96),
          (__attribute__((address_space(3))) void*)&As[3][r0 * 32], 16, 0, 0);
      __builtin_amdgcn_global_load_lds(
          (const __attribute__((address_space(1))) void*)gb,
          (__attribute__((address_space(3))) void*)&Bs[0][r0 * 32], 16, 0, 0);
      __builtin_amdgcn_global_load_lds(
          (const __attribute__((address_space(1))) void*)(gb + 32),
          (__attribute__((address_space(3))) void*)&Bs[1][r0 * 32], 16, 0, 0);
      __builtin_amdgcn_global_load_lds(
          (const __attribute__((address_space(1))) void*)(gb + 64),
          (__attribute__((address_space(3))) void*)&Bs[2][r0 * 32], 16, 0, 0);
      __builtin_amdgcn_global_load_lds(
          (const __attribute__((address_space(1))) void*)(gb + 96),
          (__attribute__((address_space(3))) void*)&Bs[3][r0 * 32], 16, 0, 0);
    }
    asm volatile("s_waitcnt vmcnt(0)" ::: "memory");
    __syncthreads();
    // half 0
    {
      shortx8 af[4], bfr[4];
#pragma unroll
      for (int i = 0; i < 4; ++i)
        af[i] = *(const shortx8*)&As[0][(wm * 64 + i * 16 + l15) * 32 + quad * 8];
#pragma unroll
      for (int j = 0; j < 4; ++j)
        bfr[j] = *(const shortx8*)&Bs[0][(wn * 64 + j * 16 + l15) * 32 + quad * 8];
#pragma unroll
      for (int i = 0; i < 4; ++i)
#pragma unroll
        for (int j = 0; j < 4; ++j)
          acc[i][j] = __builtin_amdgcn_mfma_f32_16x16x32_bf16(af[i], bfr[j], acc[i][j], 0, 0, 0);
    }
    // half 1
    {
      shortx8 af[4], bfr[4];
#pragma unroll
      for (int i = 0; i < 4; ++i)
        af[i] = *(const shortx8*)&As[1][(wm * 64 + i * 16 + l15) * 32 + quad * 8];
#pragma unroll
      for (int j = 0; j < 4; ++j)
        bfr[j] = *(const shortx8*)&Bs[1][(wn * 64 + j * 16 + l15) * 32 + quad * 8];
#pragma unroll
      for (int i = 0; i < 4; ++i)
#pragma unroll
        for (int j = 0; j < 4; ++j)
          acc[i][j] = __builtin_amdgcn_mfma_f32_16x16x32_bf16(af[i], bfr[j], acc[i][j], 0, 0, 0);
    }
    // half 2
    {
      shortx8 af[4], bfr[4];
#pragma unroll
      for (int i = 0; i < 4; ++i)
        af[i] = *(const shortx8*)&As[2][(wm * 64 + i * 16 + l15) * 32 + quad * 8];
#pragma unroll
      for (int j = 0; j < 4; ++j)
        bfr[j] = *(const shortx8*)&Bs[2][(wn * 64 + j * 16 + l15) * 32 + quad * 8];
#pragma unroll
      for (int i = 0; i < 4; ++i)
#pragma unroll
        for (int j = 0; j < 4; ++j)
          acc[i][j] = __builtin_amdgcn_mfma_f32_16x16x32_bf16(af[i], bfr[j], acc[i][j], 0, 0, 0);
    }
    // half 3
    {
      shortx8 af[4], bfr[4];
#pragma unroll
      for (int i = 0; i < 4; ++i)
        af[i] = *(const shortx8*)&As[3][(wm * 64 + i * 16 + l15) * 32 + quad * 8];
#pragma unroll
      for (int j = 0; j < 4; ++j)
        bfr[j] = *(const shortx8*)&Bs[3][(wn * 64 + j * 16 + l15) * 32 + quad * 8];
#pragma unroll
      for (int i = 0; i < 4; ++i)
#pragma unroll
        for (int j = 0; j < 4; ++j)
          acc[i][j] = __builtin_amdgcn_mfma_f32_16x16x32_bf16(af[i], bfr[j], acc[i][j], 0, 0, 0);
    }
    __syncthreads();
  }
#pragma unroll
  for (int i = 0; i < 4; ++i) {
    const int row = bm0 + wm * 64 + i * 16 + quad * 4;
#pragma unroll
    for (int j = 0; j < 4; ++j) {
      const int col = bn0 + wn * 64 + j * 16 + l15;
      const float bb = bias[col];
#pragma unroll
      for (int r = 0; r < 4; ++r) {
        float v = acc[i][j][r] + bb;
        if (RELU) v = fmaxf(v, 0.0f);
        if (RESID) v += resid[(size_t)(row + r) * N + col];
        if constexpr (sizeof(OutT) == 2)
          C[(size_t)(row + r) * N + col] = f2bf(v);
        else
          C[(size_t)(row + r) * N + col] = v;
      }
    }
  }
}

// ================= split-K flash attention =================
// Static-max softmax (scores = q.k/32, tiny; fp32 exp2 has huge headroom) makes
// chunk partials ADDITIVE: O_unnorm = sum P.V, lsum = sum p.  Each block does
// one (qb, h, b, key-chunk of <=8 tiles).  qb<8 (single chunk) writes final
// bf16 y directly; else partials go to ws and attn_reduce sums & normalizes.
//
// R3: P stored k-PERMUTED for v_cvt_pk_bf16_f32; Vt key rows permuted
// identically (exact: PV sums over k).
// R6: raw v_exp_f32, wave-uniform diag split, v_rcp_f32.  98.5 -> 88.4us.
// R11: bf16 O partials (lsum fp32) — WRITE 79->42MB, 86.5us, absmax 0.031.
// R4/R13 (QBLK=128 x2 variants): FETCH fell but dur flat — the kernel is
// bound by the per-wave dependent chain, not sync/traffic.  R8/R9 pairing
// (chain overlap via Ps reuse) failed correctness twice — retired.
// This is the best verified attention configuration (R11 verbatim).
#define ATTN_SLOTS 80           // sum over qb of ceil((qb+1)/8)
#define ATTN_SLOT_SH 4224       // shorts per slot: 64*64 bf16 O + 64 fp32 lsum

__global__ __launch_bounds__(256)
void attention_chunk(const short* __restrict__ qkv, short* __restrict__ y,
                     float* __restrict__ part) {
  constexpr int T = 2048, C = 1024, HD = 64, S3 = 3072;
  __shared__ short Ks[64 * 72];      // [key][d], pad 72
  __shared__ short Vt[64 * 72];      // [d][k'], permuted keys, pad 72
  __shared__ short Ps[4][16 * 72];   // per-wave P: [q][k'], permuted
  const int x = blockIdx.x, h = blockIdx.y, b = blockIdx.z;
  int qb, ch;
  if (x < 8)       { qb = x;                 ch = 0; }
  else if (x < 24) { qb = 8 + ((x - 8) >> 1);  ch = (x - 8) & 1; }
  else if (x < 48) { qb = 16 + (x - 24) / 3;   ch = (x - 24) % 3; }
  else             { qb = 24 + ((x - 48) >> 2); ch = (x - 48) & 3; }
  const int kt0 = ch * 8;
  const int kt1 = min(kt0 + 8, qb + 1);
  const int tid = threadIdx.x, wid = tid >> 6, lane = tid & 63;
  const int quad = lane >> 4, l15 = lane & 15;
  const size_t base = (size_t)b * T * S3;
  const int q0 = qb * 64 + wid * 16;
  // Q A-frags: A[m=lane&15][k=quad*8+j]
  const short* Qp = qkv + base + (size_t)(q0 + l15) * S3 + h * HD;
  const shortx8 qf0 = *(const shortx8*)(Qp + quad * 8);
  const shortx8 qf1 = *(const shortx8*)(Qp + 32 + quad * 8);
  floatx4 o[4] = {};
  float lsum[4] = {0.f, 0.f, 0.f, 0.f};
  const float scale2 = 0.03125f * 1.44269504088896f;  // 1/sqrt(C) * log2(e)
  const int skey = tid >> 2, sd = (tid & 3) * 16;  // K staging
  const int vkp = tid & 31, vdb = tid >> 5;        // V staging (vdb 0..7)
  const int vkE = (vkp >> 4) * 32 + (vkp & 15);    // even-k' source key row
  const short* Kbase = qkv + base + C + h * HD;
  const short* Vbase = qkv + base + 2 * C + h * HD;
  // register prefetch of tile kt0
  shortx8 pk0, pk1, pv0, pv1;
  {
    const short* Kp = Kbase + (size_t)(kt0 * 64 + skey) * S3 + sd;
    pk0 = *(const shortx8*)Kp;
    pk1 = *(const shortx8*)(Kp + 8);
    const short* Vp = Vbase + (size_t)(kt0 * 64 + vkE) * S3 + vdb * 8;
    pv0 = *(const shortx8*)Vp;            // key c   -> k' even (lo)
    pv1 = *(const shortx8*)(Vp + 16 * S3);// key c+16 -> k' odd (hi)
  }
  for (int kt = kt0; kt < kt1; ++kt) {
    const int key0 = kt * 64;
    __syncthreads();
    *(shortx8*)&Ks[skey * 72 + sd] = pk0;
    *(shortx8*)&Ks[skey * 72 + sd + 8] = pk1;
#pragma unroll
    for (int j = 0; j < 8; ++j) {
      short2 pr = make_short2(pv0[j], pv1[j]);
      *(short2*)&Vt[(vdb * 8 + j) * 72 + 2 * vkp] = pr;
    }
    __syncthreads();
    if (kt + 1 < kt1) {  // prefetch next tile
      const int kn = key0 + 64;
      const short* Kp = Kbase + (size_t)(kn + skey) * S3 + sd;
      pk0 = *(const shortx8*)Kp;
      pk1 = *(const shortx8*)(Kp + 8);
      const short* Vp = Vbase + (size_t)(kn + vkE) * S3 + vdb * 8;
      pv0 = *(const shortx8*)Vp;
      pv1 = *(const shortx8*)(Vp + 16 * S3);
    }
    floatx4 s[4];
#pragma unroll
    for (int nt = 0; nt < 4; ++nt) {
      const short* kb = &Ks[(nt * 16 + l15) * 72 + quad * 8];
      floatx4 a = {};
      a = __builtin_amdgcn_mfma_f32_16x16x32_bf16(qf0, *(const shortx8*)kb, a, 0, 0, 0);
      a = __builtin_amdgcn_mfma_f32_16x16x32_bf16(qf1, *(const shortx8*)(kb + 32), a, 0, 0, 0);
      s[nt] = a;
    }
    short* pw = &Ps[wid][0];
    if (kt != qb) {   // fast path: no causal mask in this tile (wave-uniform)
#pragma unroll
      for (int r = 0; r < 4; ++r) {
        const float p0 = __builtin_amdgcn_exp2f(s[0][r] * scale2);
        const float p1 = __builtin_amdgcn_exp2f(s[1][r] * scale2);
        const float p2 = __builtin_amdgcn_exp2f(s[2][r] * scale2);
        const float p3 = __builtin_amdgcn_exp2f(s[3][r] * scale2);
        lsum[r] += (p0 + p1) + (p2 + p3);
        unsigned w0, w1;
        asm("v_cvt_pk_bf16_f32 %0, %1, %2" : "=v"(w0) : "v"(p0), "v"(p1));
        asm("v_cvt_pk_bf16_f32 %0, %1, %2" : "=v"(w1) : "v"(p2), "v"(p3));
        unsigned* prow = (unsigned*)&pw[(quad * 4 + r) * 72];
        prow[l15] = w0;        // k' = 2*l15, 2*l15+1        (cols l15, l15+16)
        prow[16 + l15] = w1;   // k' = 32+2*l15, 32+2*l15+1  (cols l15+32, l15+48)
      }
    } else {          // diag tile: mask key > q
#pragma unroll
      for (int r = 0; r < 4; ++r) {
        const int q = q0 + quad * 4 + r;
        float pr[4];
#pragma unroll
        for (int nt = 0; nt < 4; ++nt) {
          float sv = s[nt][r] * scale2;
          if (key0 + nt * 16 + l15 > q) sv = -INFINITY;
          pr[nt] = __builtin_amdgcn_exp2f(sv);  // v_exp_f32(-inf)=0
        }
        lsum[r] += (pr[0] + pr[1]) + (pr[2] + pr[3]);
        unsigned w0, w1;
        asm("v_cvt_pk_bf16_f32 %0, %1, %2" : "=v"(w0) : "v"(pr[0]), "v"(pr[1]));
        asm("v_cvt_pk_bf16_f32 %0, %1, %2" : "=v"(w1) : "v"(pr[2]), "v"(pr[3]));
        unsigned* prow = (unsigned*)&pw[(quad * 4 + r) * 72];
        prow[l15] = w0;
        prow[16 + l15] = w1;
      }
    }
    asm volatile("s_waitcnt lgkmcnt(0)" ::: "memory");
#pragma unroll
    for (int kf = 0; kf < 2; ++kf) {
      const shortx8 pa = *(const shortx8*)&Ps[wid][l15 * 72 + kf * 32 + quad * 8];
#pragma unroll
      for (int dt = 0; dt < 4; ++dt) {
        const shortx8 vb = *(const shortx8*)&Vt[(dt * 16 + l15) * 72 + kf * 32 + quad * 8];
        o[dt] = __builtin_amdgcn_mfma_f32_16x16x32_bf16(pa, vb, o[dt], 0, 0, 0);
      }
    }
  }
  // reduce lsum over the 16 lanes of each quad group
  float ls[4];
#pragma unroll
  for (int r = 0; r < 4; ++r) {
    float s = lsum[r];
    for (int off = 1; off < 16; off <<= 1) s += __shfl_xor(s, off);
    ls[r] = s;
  }
  if (x < 8) {  // single chunk -> final output
    float inv[4];
#pragma unroll
    for (int r = 0; r < 4; ++r) inv[r] = __builtin_amdgcn_rcpf(ls[r]);
#pragma unroll
    for (int dt = 0; dt < 4; ++dt)
#pragma unroll
      for (int r = 0; r < 4; ++r) {
        const int q = q0 + quad * 4 + r;
        y[((size_t)b * T + q) * C + h * HD + dt * 16 + l15] =
            f2bf(o[dt][r] * inv[r]);
      }
  } else {      // bf16 O partials + fp32 lsum
    short* pp = (short*)part +
                ((size_t)(b * 16 + h) * ATTN_SLOTS + x) * ATTN_SLOT_SH;
    float* pl = (float*)(pp + 4096);
    const int qw = wid * 16;
#pragma unroll
    for (int dt = 0; dt < 4; ++dt)
#pragma unroll
      for (int r = 0; r < 4; ++r)
        pp[(qw + quad * 4 + r) * 64 + dt * 16 + l15] = f2bf(o[dt][r]);
    if (l15 == 0)
#pragma unroll
      for (int r = 0; r < 4; ++r)
        pl[qw + quad * 4 + r] = ls[r];
  }
}

__global__ __launch_bounds__(256)
void attn_reduce(const float* __restrict__ part, short* __restrict__ y) {
  constexpr int T = 2048, C = 1024;
  const int qb = 8 + blockIdx.x, h = blockIdx.y, b = blockIdx.z;
  const int c = qb / 8 + 1;  // 2..4 chunks
  int slot0;
  if (qb < 16)      slot0 = 8 + 2 * (qb - 8);
  else if (qb < 24) slot0 = 24 + 3 * (qb - 16);
  else              slot0 = 48 + 4 * (qb - 24);
  const short* rb = (const short*)part +
                    ((size_t)(b * 16 + h) * ATTN_SLOTS + slot0) * ATTN_SLOT_SH;
  const int t = threadIdx.x;
  const int q = t >> 2, dg = (t & 3) * 16;
  float acc[16] = {};
  float ls = 0.f;
  for (int ci = 0; ci < c; ++ci) {
    const short* pp = rb + (size_t)ci * ATTN_SLOT_SH;
    const shortx8 v0 = *(const shortx8*)(pp + q * 64 + dg);
    const shortx8 v1 = *(const shortx8*)(pp + q * 64 + dg + 8);
#pragma unroll
    for (int i = 0; i < 8; ++i) {
      acc[i] += bf2f(v0[i]);
      acc[8 + i] += bf2f(v1[i]);
    }
    ls += *(const float*)(pp + 4096 + 2 * q);
  }
  const float inv = __builtin_amdgcn_rcpf(ls);
  short o16[16];
#pragma unroll
  for (int i = 0; i < 16; ++i) o16[i] = f2bf(acc[i] * inv);
  short* yp = y + ((size_t)b * T + qb * 64 + q) * C + h * 64 + dg;
  *(shortx8*)yp = *(shortx8*)&o16[0];
  *(shortx8*)(yp + 8) = *(shortx8*)&o16[8];
}

// ---- fallback single-pass attention (used only if ws too small) ----
__global__ __launch_bounds__(256)
void attention_kernel(const short* __restrict__ qkv, short* __restrict__ y) {
  constexpr int T = 2048, C = 1024, HD = 64, S3 = 3072;
  __shared__ short Ks[64 * 72];
  __shared__ short Vt[64 * 72];
  __shared__ short Ps[4][16 * 72];
  const int qb = blockIdx.x, h = blockIdx.y, b = blockIdx.z;
  const int tid = threadIdx.x, wid = tid >> 6, lane = tid & 63;
  const int quad = lane >> 4, l15 = lane & 15;
  const size_t base = (size_t)b * T * S3;
  const int q0 = qb * 64 + wid * 16;
  const short* Qp = qkv + base + (size_t)(q0 + l15) * S3 + h * HD;
  const shortx8 qf0 = *(const shortx8*)(Qp + quad * 8);
  const shortx8 qf1 = *(const shortx8*)(Qp + 32 + quad * 8);
  floatx4 o[4] = {};
  float lsum[4] = {0.f, 0.f, 0.f, 0.f};
  const float scale2 = 0.03125f * 1.44269504088896f;
  const int skey = tid >> 2, sd = (tid & 3) * 16;
  const int vkp = tid & 31, vdb = tid >> 5;
  for (int kt = 0; kt <= qb; ++kt) {
    const int key0 = kt * 64;
    __syncthreads();
    {
      const short* Kp = qkv + base + (size_t)(key0 + skey) * S3 + C + h * HD + sd;
      shortx8 ka = *(const shortx8*)Kp;
      shortx8 kb = *(const shortx8*)(Kp + 8);
      *(shortx8*)&Ks[skey * 72 + sd] = ka;
      *(shortx8*)&Ks[skey * 72 + sd + 8] = kb;
      const short* Vp = qkv + base + (size_t)(key0 + 2 * vkp) * S3 + 2 * C + h * HD + vdb * 8;
      shortx8 va = *(const shortx8*)Vp;
      shortx8 vb = *(const shortx8*)(Vp + S3);
#pragma unroll
      for (int j = 0; j < 8; ++j) {
        short2 pr = make_short2(va[j], vb[j]);
        *(short2*)&Vt[(vdb * 8 + j) * 72 + 2 * vkp] = pr;
      }
    }
    __syncthreads();
    floatx4 s[4];
#pragma unroll
    for (int nt = 0; nt < 4; ++nt) {
      const short* kb = &Ks[(nt * 16 + l15) * 72 + quad * 8];
      floatx4 a = {};
      a = __builtin_amdgcn_mfma_f32_16x16x32_bf16(qf0, *(const shortx8*)kb, a, 0, 0, 0);
      a = __builtin_amdgcn_mfma_f32_16x16x32_bf16(qf1, *(const shortx8*)(kb + 32), a, 0, 0, 0);
      s[nt] = a;
    }
    short* pw = &Ps[wid][0];
    const bool diag = (kt == qb);
#pragma unroll
    for (int nt = 0; nt < 4; ++nt)
#pragma unroll
      for (int r = 0; r < 4; ++r) {
        float sv = s[nt][r] * scale2;
        if (diag) {
          const int key = key0 + nt * 16 + l15;
          const int q = q0 + quad * 4 + r;
          if (key > q) sv = -INFINITY;
        }
        const float p = __builtin_amdgcn_exp2f(sv);
        lsum[r] += p;
        pw[(quad * 4 + r) * 72 + nt * 16 + l15] = f2bf(p);
      }
    asm volatile("s_waitcnt lgkmcnt(0)" ::: "memory");
#pragma unroll
    for (int kf = 0; kf < 2; ++kf) {
      const shortx8 pa = *(const shortx8*)&Ps[wid][l15 * 72 + kf * 32 + quad * 8];
#pragma unroll
      for (int dt = 0; dt < 4; ++dt) {
        const shortx8 vb = *(const shortx8*)&Vt[(dt * 16 + l15) * 72 + kf * 32 + quad * 8];
        o[dt] = __builtin_amdgcn_mfma_f32_16x16x32_bf16(pa, vb, o[dt], 0, 0, 0);
      }
    }
  }
  float inv[4];
#pragma unroll
  for (int r = 0; r < 4; ++r) {
    float s = lsum[r];
    for (int off = 1; off < 16; off <<= 1) s += __shfl_xor(s, off);
    inv[r] = __builtin_amdgcn_rcpf(s);
  }
#pragma unroll
  for (int dt = 0; dt < 4; ++dt)
#pragma unroll
    for (int r = 0; r < 4; ++r) {
      const int q = q0 + quad * 4 + r;
      y[((size_t)b * T + q) * C + h * HD + dt * 16 + l15] = f2bf(o[dt][r] * inv[r]);
    }
}

extern "C" void kernel_launch(void* const* d_in, const int* in_sizes, int n_in,
                              void* d_out, int out_size, void* d_ws, size_t ws_size,
                              hipStream_t stream) {
  const float* x      = (const float*)d_in[0];
  const float* ln1_w  = (const float*)d_in[1];
  const float* ln1_b  = (const float*)d_in[2];
  const float* qkv_w  = (const float*)d_in[3];
  const float* qkv_b  = (const float*)d_in[4];
  const float* proj_w = (const float*)d_in[5];
  const float* proj_b = (const float*)d_in[6];
  const float* ln2_w  = (const float*)d_in[7];
  const float* ln2_b  = (const float*)d_in[8];
  const float* ff_w1  = (const float*)d_in[9];
  const float* ff_b1  = (const float*)d_in[10];
  const float* ff_w2  = (const float*)d_in[11];
  const float* ff_b2  = (const float*)d_in[12];
  float* out = (float*)d_out;

  char* p = (char*)d_ws;
  short* wT_qkv  = (short*)p; p += (size_t)3072 * 1024 * 2;
  short* wT_proj = (short*)p; p += (size_t)1024 * 1024 * 2;
  short* wT_ff1  = (short*)p; p += (size_t)4096 * 1024 * 2;
  short* wT_ff2  = (short*)p; p += (size_t)1024 * 4096 * 2;
  short* act16   = (short*)p; p += (size_t)8192 * 1024 * 2;  // h -> y -> h2
  short* big     = (short*)p; p += (size_t)8192 * 4096 * 2;  // qkv -> ff act
  float* part    = (float*)p;  // attn partials (43 MB, bf16 O + fp32 lsum)
  const size_t need = (size_t)(p - (char*)d_ws) +
                      (size_t)64 * ATTN_SLOTS * ATTN_SLOT_SH * 2;
  const bool split = (ws_size >= need);

  // weights -> bf16 transposed [N][K]
  transpose_cast<<<dim3(96, 32), 256, 0, stream>>>(qkv_w, wT_qkv, 1024, 3072);
  transpose_cast<<<dim3(32, 32), 256, 0, stream>>>(proj_w, wT_proj, 1024, 1024);
  transpose_cast<<<dim3(128, 32), 256, 0, stream>>>(ff_w1, wT_ff1, 1024, 4096);
  transpose_cast<<<dim3(32, 128), 256, 0, stream>>>(ff_w2, wT_ff2, 4096, 1024);

  // h = LN1(x)
  layernorm_kernel<<<8192, 256, 0, stream>>>(x, ln1_w, ln1_b, act16);
  // qkv = h @ qkv_w + qkv_b           [8192,3072]
  gemm_bt<0, short><<<dim3(24, 64), 256, 0, stream>>>(
      act16, 1024, wT_qkv, 1024, qkv_b, nullptr, big, 8192, 3072, 1024);
  // y = causal_attention(qkv)  — split-K if ws fits, else single-pass
  if (split) {
    attention_chunk<<<dim3(ATTN_SLOTS, 16, 4), 256, 0, stream>>>(big, act16, part);
    attn_reduce<<<dim3(24, 16, 4), 256, 0, stream>>>(part, act16);
  } else {
    attention_kernel<<<dim3(32, 16, 4), 256, 0, stream>>>(big, act16);
  }
  // x2 = x + y @ proj_w + proj_b  -> d_out (fp32)
  gemm_bt<2, float><<<dim3(8, 64), 256, 0, stream>>>(
      act16, 1024, wT_proj, 1024, proj_b, x, out, 8192, 1024, 1024);
  // h2 = LN2(x2)
  layernorm_kernel<<<8192, 256, 0, stream>>>(out, ln2_w, ln2_b, act16);
  // a = relu(h2 @ ff_w1 + ff_b1)      [8192,4096]
  gemm_bt<1, short><<<dim3(32, 64), 256, 0, stream>>>(
      act16, 1024, wT_ff1, 1024, ff_b1, nullptr, big, 8192, 4096, 1024);
  // out = x2 + a @ ff_w2 + ff_b2  — BK=128 (16 iters; grid-capped 2/CU so
  // 64KB LDS is free; resid read-before-write, same thread)
  gemm_bt_k128<2, float><<<dim3(8, 64), 256, 0, stream>>>(
      big, 4096, wT_ff2, 4096, ff_b2, out, out, 8192, 1024, 4096);
}

// Round 16
// 481.171 us; speedup vs baseline: 1.0866x; 1.0035x over previous
//
#include <hip/hip_runtime.h>

// Decoder block: x -> LN1 -> QKV GEMM -> causal MHA -> proj(+x) -> LN2 -> FFN(+res)
// B=4 T=2048 C=1024 H=16 hd=64.  All MFMA compute in bf16, fp32 accumulate.
// FINAL (R16 = R14 verbatim, verified 482.9us):
//  - gemm_bt: 128x128 BK=64 (2 sub-tiles) for qkv/ff1
//  - gemm_bt_k128: BK=128 (4 sub-tiles) for grid-capped ff2 (2 blocks/CU)
//  - attention: split-K static-max softmax, cvt_pk P-perm, raw v_exp_f32,
//    bf16 partials.  R15's fused-transpose + k128-proj crashed -> reverted.

typedef __attribute__((ext_vector_type(8))) short shortx8;   // 8 bf16 (4 VGPR)
typedef __attribute__((ext_vector_type(4))) float floatx4;   // MFMA C/D

__device__ __forceinline__ short f2bf(float f) {
  unsigned u = __builtin_bit_cast(unsigned, f);
  u = (u + 0x7fffu + ((u >> 16) & 1u)) >> 16;   // RNE
  return (short)u;
}
__device__ __forceinline__ float bf2f(short s) {
  return __builtin_bit_cast(float, (unsigned)((unsigned short)s) << 16);
}

// ---- weight transpose + cast: in [K][N] f32 -> out [N][K] bf16 ----
__global__ __launch_bounds__(256)
void transpose_cast(const float* __restrict__ in, short* __restrict__ out,
                    int K, int N) {
  __shared__ float tile[32][33];
  const int n0 = blockIdx.x * 32, k0 = blockIdx.y * 32;
  const int tx = threadIdx.x & 31, ty = threadIdx.x >> 5;  // 32x8
  for (int i = 0; i < 32; i += 8)
    tile[ty + i][tx] = in[(size_t)(k0 + ty + i) * N + n0 + tx];
  __syncthreads();
  for (int i = 0; i < 32; i += 8)
    out[(size_t)(n0 + ty + i) * K + k0 + tx] = f2bf(tile[tx][ty + i]);
}

// ---- layernorm: f32 in -> bf16 out, C=1024, one block (256 thr) per row ----
__global__ __launch_bounds__(256)
void layernorm_kernel(const float* __restrict__ x, const float* __restrict__ w,
                      const float* __restrict__ bta, short* __restrict__ out) {
  const int C = 1024;
  const int row = blockIdx.x;
  const float4 v = ((const float4*)(x + (size_t)row * C))[threadIdx.x];
  float s1 = v.x + v.y + v.z + v.w;
  float s2 = v.x * v.x + v.y * v.y + v.z * v.z + v.w * v.w;
  for (int m = 1; m < 64; m <<= 1) { s1 += __shfl_xor(s1, m); s2 += __shfl_xor(s2, m); }
  __shared__ float r1[4], r2[4];
  const int wid = threadIdx.x >> 6, lane = threadIdx.x & 63;
  if (lane == 0) { r1[wid] = s1; r2[wid] = s2; }
  __syncthreads();
  s1 = r1[0] + r1[1] + r1[2] + r1[3];
  s2 = r2[0] + r2[1] + r2[2] + r2[3];
  const float mean = s1 * (1.0f / C);
  const float var = s2 * (1.0f / C) - mean * mean;
  const float rs = rsqrtf(var + 1e-5f);
  const float4 wv = ((const float4*)w)[threadIdx.x];
  const float4 bv = ((const float4*)bta)[threadIdx.x];
  short4 o;
  o.x = f2bf((v.x - mean) * rs * wv.x + bv.x);
  o.y = f2bf((v.y - mean) * rs * wv.y + bv.y);
  o.z = f2bf((v.z - mean) * rs * wv.z + bv.z);
  o.w = f2bf((v.w - mean) * rs * wv.w + bv.w);
  *(short4*)(out + (size_t)row * C + threadIdx.x * 4) = o;
}

// ---- MFMA GEMM: C = A[M,K]@Bt[N,K]^T + bias (+resid)(+relu)
// 128x128 tile, BK=64 as TWO independent BK=32 sub-tiles (hand-written,
// verbatim R6 — best verified).  Used by qkv/proj/ff1.
// FLAGS: bit0=relu, bit1=resid(fp32).  lda/ldb = row strides of A / Bt.
template<int FLAGS, typename OutT>
__global__ __launch_bounds__(256, 4)
void gemm_bt(const short* __restrict__ A, int lda,
             const short* __restrict__ Bt, int ldb,
             const float* __restrict__ bias, const float* __restrict__ resid,
             OutT* __restrict__ C, int M, int N, int K) {
  constexpr bool RELU = (FLAGS & 1) != 0;
  constexpr bool RESID = (FLAGS & 2) != 0;
  __shared__ short As[2][128 * 32];   // [khalf][m][k]
  __shared__ short Bs[2][128 * 32];   // [khalf][n][k]
  int bmi, bni;
  {
    const int nb = gridDim.x, mb = gridDim.y;
    const int g = blockIdx.x + nb * blockIdx.y;
    if ((mb & 7) == 0) {
      const int xcd = g & 7, l = g >> 3;      // 8 XCDs, round-robin dispatch
      bmi = xcd * (mb >> 3) + l / nb;
      bni = l % nb;
    } else { bmi = blockIdx.y; bni = blockIdx.x; }
  }
  const int bm0 = bmi * 128, bn0 = bni * 128;
  const int tid = threadIdx.x, wid = tid >> 6, lane = tid & 63;
  const int quad = lane >> 4, l15 = lane & 15;
  const int wm = wid & 1, wn = wid >> 1;
  const int srow = lane >> 2, scol = (lane & 3) * 8;
  floatx4 acc[4][4] = {};
  for (int k0 = 0; k0 < K; k0 += 64) {
    for (int i = 0; i < 2; ++i) {
      const int r0 = (wid * 2 + i) * 16;
      const short* ga = A + (size_t)(bm0 + r0 + srow) * lda + k0 + scol;
      const short* gb = Bt + (size_t)(bn0 + r0 + srow) * ldb + k0 + scol;
      __builtin_amdgcn_global_load_lds(
          (const __attribute__((address_space(1))) void*)ga,
          (__attribute__((address_space(3))) void*)&As[0][r0 * 32], 16, 0, 0);
      __builtin_amdgcn_global_load_lds(
          (const __attribute__((address_space(1))) void*)(ga + 32),
          (__attribute__((address_space(3))) void*)&As[1][r0 * 32], 16, 0, 0);
      __builtin_amdgcn_global_load_lds(
          (const __attribute__((address_space(1))) void*)gb,
          (__attribute__((address_space(3))) void*)&Bs[0][r0 * 32], 16, 0, 0);
      __builtin_amdgcn_global_load_lds(
          (const __attribute__((address_space(1))) void*)(gb + 32),
          (__attribute__((address_space(3))) void*)&Bs[1][r0 * 32], 16, 0, 0);
    }
    asm volatile("s_waitcnt vmcnt(0)" ::: "memory");
    __syncthreads();
    // half 0
    {
      shortx8 af[4], bfr[4];
#pragma unroll
      for (int i = 0; i < 4; ++i)
        af[i] = *(const shortx8*)&As[0][(wm * 64 + i * 16 + l15) * 32 + quad * 8];
#pragma unroll
      for (int j = 0; j < 4; ++j)
        bfr[j] = *(const shortx8*)&Bs[0][(wn * 64 + j * 16 + l15) * 32 + quad * 8];
#pragma unroll
      for (int i = 0; i < 4; ++i)
#pragma unroll
        for (int j = 0; j < 4; ++j)
          acc[i][j] = __builtin_amdgcn_mfma_f32_16x16x32_bf16(af[i], bfr[j], acc[i][j], 0, 0, 0);
    }
    // half 1
    {
      shortx8 af[4], bfr[4];
#pragma unroll
      for (int i = 0; i < 4; ++i)
        af[i] = *(const shortx8*)&As[1][(wm * 64 + i * 16 + l15) * 32 + quad * 8];
#pragma unroll
      for (int j = 0; j < 4; ++j)
        bfr[j] = *(const shortx8*)&Bs[1][(wn * 64 + j * 16 + l15) * 32 + quad * 8];
#pragma unroll
      for (int i = 0; i < 4; ++i)
#pragma unroll
        for (int j = 0; j < 4; ++j)
          acc[i][j] = __builtin_amdgcn_mfma_f32_16x16x32_bf16(af[i], bfr[j], acc[i][j], 0, 0, 0);
    }
    __syncthreads();
  }
  // epilogue: D row = (lane>>4)*4 + reg, col = lane&15 (m89/m91-verified)
#pragma unroll
  for (int i = 0; i < 4; ++i) {
    const int row = bm0 + wm * 64 + i * 16 + quad * 4;
#pragma unroll
    for (int j = 0; j < 4; ++j) {
      const int col = bn0 + wn * 64 + j * 16 + l15;
      const float bb = bias[col];
#pragma unroll
      for (int r = 0; r < 4; ++r) {
        float v = acc[i][j][r] + bb;
        if (RELU) v = fmaxf(v, 0.0f);
        if (RESID) v += resid[(size_t)(row + r) * N + col];
        if constexpr (sizeof(OutT) == 2)
          C[(size_t)(row + r) * N + col] = f2bf(v);
        else
          C[(size_t)(row + r) * N + col] = v;
      }
    }
  }
}

// ---- BK=128 GEMM (FOUR hand-unrolled BK=32 sub-tiles) for ff2 ONLY ----
// ff2 (K=4096, grid 512 = 2 blocks/CU, grid-capped): 64KB LDS is free, and
// 16 K-iters (vs 64) quarter the vmcnt(0)+barrier drains.  R14 verified
// per-dispatch: ff2 left the top-5 (<86.8us vs 90 at BK=64).
template<int FLAGS, typename OutT>
__global__ __launch_bounds__(256, 4)
void gemm_bt_k128(const short* __restrict__ A, int lda,
                  const short* __restrict__ Bt, int ldb,
                  const float* __restrict__ bias, const float* __restrict__ resid,
                  OutT* __restrict__ C, int M, int N, int K) {
  constexpr bool RELU = (FLAGS & 1) != 0;
  constexpr bool RESID = (FLAGS & 2) != 0;
  __shared__ short As[4][128 * 32];   // [khalf][m][k]
  __shared__ short Bs[4][128 * 32];   // [khalf][n][k]
  int bmi, bni;
  {
    const int nb = gridDim.x, mb = gridDim.y;
    const int g = blockIdx.x + nb * blockIdx.y;
    if ((mb & 7) == 0) {
      const int xcd = g & 7, l = g >> 3;
      bmi = xcd * (mb >> 3) + l / nb;
      bni = l % nb;
    } else { bmi = blockIdx.y; bni = blockIdx.x; }
  }
  const int bm0 = bmi * 128, bn0 = bni * 128;
  const int tid = threadIdx.x, wid = tid >> 6, lane = tid & 63;
  const int quad = lane >> 4, l15 = lane & 15;
  const int wm = wid & 1, wn = wid >> 1;
  const int srow = lane >> 2, scol = (lane & 3) * 8;
  floatx4 acc[4][4] = {};
  for (int k0 = 0; k0 < K; k0 += 128) {
    for (int i = 0; i < 2; ++i) {
      const int r0 = (wid * 2 + i) * 16;
      const short* ga = A + (size_t)(bm0 + r0 + srow) * lda + k0 + scol;
      const short* gb = Bt + (size_t)(bn0 + r0 + srow) * ldb + k0 + scol;
      __builtin_amdgcn_global_load_lds(
          (const __attribute__((address_space(1))) void*)ga,
          (__attribute__((address_space(3))) void*)&As[0][r0 * 32], 16, 0, 0);
      __builtin_amdgcn_global_load_lds(
          (const __attribute__((address_space(1))) void*)(ga + 32),
          (__attribute__((address_space(3))) void*)&As[1][r0 * 32], 16, 0, 0);
      __builtin_amdgcn_global_load_lds(
          (const __attribute__((address_space(1))) void*)(ga + 64),
          (__attribute__((address_space(3))) void*)&As[2][r0 * 32], 16, 0, 0);
      __builtin_amdgcn_global_load_lds(
          (const __attribute__((address_space(1))) void*)(ga + 96),
          (__attribute__((address_space(3))) void*)&As[3][r0 * 32], 16, 0, 0);
      __builtin_amdgcn_global_load_lds(
          (const __attribute__((address_space(1))) void*)gb,
          (__attribute__((address_space(3))) void*)&Bs[0][r0 * 32], 16, 0, 0);
      __builtin_amdgcn_global_load_lds(
          (const __attribute__((address_space(1))) void*)(gb + 32),
          (__attribute__((address_space(3))) void*)&Bs[1][r0 * 32], 16, 0, 0);
      __builtin_amdgcn_global_load_lds(
          (const __attribute__((address_space(1))) void*)(gb + 64),
          (__attribute__((address_space(3))) void*)&Bs[2][r0 * 32], 16, 0, 0);
      __builtin_amdgcn_global_load_lds(
          (const __attribute__((address_space(1))) void*)(gb + 96),
          (__attribute__((address_space(3))) void*)&Bs[3][r0 * 32], 16, 0, 0);
    }
    asm volatile("s_waitcnt vmcnt(0)" ::: "memory");
    __syncthreads();
    // half 0
    {
      shortx8 af[4], bfr[4];
#pragma unroll
      for (int i = 0; i < 4; ++i)
        af[i] = *(const shortx8*)&As[0][(wm * 64 + i * 16 + l15) * 32 + quad * 8];
#pragma unroll
      for (int j = 0; j < 4; ++j)
        bfr[j] = *(const shortx8*)&Bs[0][(wn * 64 + j * 16 + l15) * 32 + quad * 8];
#pragma unroll
      for (int i = 0; i < 4; ++i)
#pragma unroll
        for (int j = 0; j < 4; ++j)
          acc[i][j] = __builtin_amdgcn_mfma_f32_16x16x32_bf16(af[i], bfr[j], acc[i][j], 0, 0, 0);
    }
    // half 1
    {
      shortx8 af[4], bfr[4];
#pragma unroll
      for (int i = 0; i < 4; ++i)
        af[i] = *(const shortx8*)&As[1][(wm * 64 + i * 16 + l15) * 32 + quad * 8];
#pragma unroll
      for (int j = 0; j < 4; ++j)
        bfr[j] = *(const shortx8*)&Bs[1][(wn * 64 + j * 16 + l15) * 32 + quad * 8];
#pragma unroll
      for (int i = 0; i < 4; ++i)
#pragma unroll
        for (int j = 0; j < 4; ++j)
          acc[i][j] = __builtin_amdgcn_mfma_f32_16x16x32_bf16(af[i], bfr[j], acc[i][j], 0, 0, 0);
    }
    // half 2
    {
      shortx8 af[4], bfr[4];
#pragma unroll
      for (int i = 0; i < 4; ++i)
        af[i] = *(const shortx8*)&As[2][(wm * 64 + i * 16 + l15) * 32 + quad * 8];
#pragma unroll
      for (int j = 0; j < 4; ++j)
        bfr[j] = *(const shortx8*)&Bs[2][(wn * 64 + j * 16 + l15) * 32 + quad * 8];
#pragma unroll
      for (int i = 0; i < 4; ++i)
#pragma unroll
        for (int j = 0; j < 4; ++j)
          acc[i][j] = __builtin_amdgcn_mfma_f32_16x16x32_bf16(af[i], bfr[j], acc[i][j], 0, 0, 0);
    }
    // half 3
    {
      shortx8 af[4], bfr[4];
#pragma unroll
      for (int i = 0; i < 4; ++i)
        af[i] = *(const shortx8*)&As[3][(wm * 64 + i * 16 + l15) * 32 + quad * 8];
#pragma unroll
      for (int j = 0; j < 4; ++j)
        bfr[j] = *(const shortx8*)&Bs[3][(wn * 64 + j * 16 + l15) * 32 + quad * 8];
#pragma unroll
      for (int i = 0; i < 4; ++i)
#pragma unroll
        for (int j = 0; j < 4; ++j)
          acc[i][j] = __builtin_amdgcn_mfma_f32_16x16x32_bf16(af[i], bfr[j], acc[i][j], 0, 0, 0);
    }
    __syncthreads();
  }
#pragma unroll
  for (int i = 0; i < 4; ++i) {
    const int row = bm0 + wm * 64 + i * 16 + quad * 4;
#pragma unroll
    for (int j = 0; j < 4; ++j) {
      const int col = bn0 + wn * 64 + j * 16 + l15;
      const float bb = bias[col];
#pragma unroll
      for (int r = 0; r < 4; ++r) {
        float v = acc[i][j][r] + bb;
        if (RELU) v = fmaxf(v, 0.0f);
        if (RESID) v += resid[(size_t)(row + r) * N + col];
        if constexpr (sizeof(OutT) == 2)
          C[(size_t)(row + r) * N + col] = f2bf(v);
        else
          C[(size_t)(row + r) * N + col] = v;
      }
    }
  }
}

// ================= split-K flash attention =================
// Static-max softmax (scores = q.k/32, tiny; fp32 exp2 has huge headroom) makes
// chunk partials ADDITIVE: O_unnorm = sum P.V, lsum = sum p.  Each block does
// one (qb, h, b, key-chunk of <=8 tiles).  qb<8 (single chunk) writes final
// bf16 y directly; else partials go to ws and attn_reduce sums & normalizes.
//
// R3: P stored k-PERMUTED for v_cvt_pk_bf16_f32; Vt key rows permuted
// identically (exact: PV sums over k).
// R6: raw v_exp_f32, wave-uniform diag split, v_rcp_f32.  98.5 -> 88.4us.
// R11: bf16 O partials (lsum fp32) — WRITE 79->42MB, 86.5us, absmax 0.031.
// Bound by the per-wave dependent chain (R4/R12/R13 restructures all flat).
#define ATTN_SLOTS 80           // sum over qb of ceil((qb+1)/8)
#define ATTN_SLOT_SH 4224       // shorts per slot: 64*64 bf16 O + 64 fp32 lsum

__global__ __launch_bounds__(256)
void attention_chunk(const short* __restrict__ qkv, short* __restrict__ y,
                     float* __restrict__ part) {
  constexpr int T = 2048, C = 1024, HD = 64, S3 = 3072;
  __shared__ short Ks[64 * 72];      // [key][d], pad 72
  __shared__ short Vt[64 * 72];      // [d][k'], permuted keys, pad 72
  __shared__ short Ps[4][16 * 72];   // per-wave P: [q][k'], permuted
  const int x = blockIdx.x, h = blockIdx.y, b = blockIdx.z;
  int qb, ch;
  if (x < 8)       { qb = x;                 ch = 0; }
  else if (x < 24) { qb = 8 + ((x - 8) >> 1);  ch = (x - 8) & 1; }
  else if (x < 48) { qb = 16 + (x - 24) / 3;   ch = (x - 24) % 3; }
  else             { qb = 24 + ((x - 48) >> 2); ch = (x - 48) & 3; }
  const int kt0 = ch * 8;
  const int kt1 = min(kt0 + 8, qb + 1);
  const int tid = threadIdx.x, wid = tid >> 6, lane = tid & 63;
  const int quad = lane >> 4, l15 = lane & 15;
  const size_t base = (size_t)b * T * S3;
  const int q0 = qb * 64 + wid * 16;
  // Q A-frags: A[m=lane&15][k=quad*8+j]
  const short* Qp = qkv + base + (size_t)(q0 + l15) * S3 + h * HD;
  const shortx8 qf0 = *(const shortx8*)(Qp + quad * 8);
  const shortx8 qf1 = *(const shortx8*)(Qp + 32 + quad * 8);
  floatx4 o[4] = {};
  float lsum[4] = {0.f, 0.f, 0.f, 0.f};
  const float scale2 = 0.03125f * 1.44269504088896f;  // 1/sqrt(C) * log2(e)
  const int skey = tid >> 2, sd = (tid & 3) * 16;  // K staging
  const int vkp = tid & 31, vdb = tid >> 5;        // V staging (vdb 0..7)
  const int vkE = (vkp >> 4) * 32 + (vkp & 15);    // even-k' source key row
  const short* Kbase = qkv + base + C + h * HD;
  const short* Vbase = qkv + base + 2 * C + h * HD;
  // register prefetch of tile kt0
  shortx8 pk0, pk1, pv0, pv1;
  {
    const short* Kp = Kbase + (size_t)(kt0 * 64 + skey) * S3 + sd;
    pk0 = *(const shortx8*)Kp;
    pk1 = *(const shortx8*)(Kp + 8);
    const short* Vp = Vbase + (size_t)(kt0 * 64 + vkE) * S3 + vdb * 8;
    pv0 = *(const shortx8*)Vp;            // key c   -> k' even (lo)
    pv1 = *(const shortx8*)(Vp + 16 * S3);// key c+16 -> k' odd (hi)
  }
  for (int kt = kt0; kt < kt1; ++kt) {
    const int key0 = kt * 64;
    __syncthreads();
    *(shortx8*)&Ks[skey * 72 + sd] = pk0;
    *(shortx8*)&Ks[skey * 72 + sd + 8] = pk1;
#pragma unroll
    for (int j = 0; j < 8; ++j) {
      short2 pr = make_short2(pv0[j], pv1[j]);
      *(short2*)&Vt[(vdb * 8 + j) * 72 + 2 * vkp] = pr;
    }
    __syncthreads();
    if (kt + 1 < kt1) {  // prefetch next tile
      const int kn = key0 + 64;
      const short* Kp = Kbase + (size_t)(kn + skey) * S3 + sd;
      pk0 = *(const shortx8*)Kp;
      pk1 = *(const shortx8*)(Kp + 8);
      const short* Vp = Vbase + (size_t)(kn + vkE) * S3 + vdb * 8;
      pv0 = *(const shortx8*)Vp;
      pv1 = *(const shortx8*)(Vp + 16 * S3);
    }
    floatx4 s[4];
#pragma unroll
    for (int nt = 0; nt < 4; ++nt) {
      const short* kb = &Ks[(nt * 16 + l15) * 72 + quad * 8];
      floatx4 a = {};
      a = __builtin_amdgcn_mfma_f32_16x16x32_bf16(qf0, *(const shortx8*)kb, a, 0, 0, 0);
      a = __builtin_amdgcn_mfma_f32_16x16x32_bf16(qf1, *(const shortx8*)(kb + 32), a, 0, 0, 0);
      s[nt] = a;
    }
    short* pw = &Ps[wid][0];
    if (kt != qb) {   // fast path: no causal mask in this tile (wave-uniform)
#pragma unroll
      for (int r = 0; r < 4; ++r) {
        const float p0 = __builtin_amdgcn_exp2f(s[0][r] * scale2);
        const float p1 = __builtin_amdgcn_exp2f(s[1][r] * scale2);
        const float p2 = __builtin_amdgcn_exp2f(s[2][r] * scale2);
        const float p3 = __builtin_amdgcn_exp2f(s[3][r] * scale2);
        lsum[r] += (p0 + p1) + (p2 + p3);
        unsigned w0, w1;
        asm("v_cvt_pk_bf16_f32 %0, %1, %2" : "=v"(w0) : "v"(p0), "v"(p1));
        asm("v_cvt_pk_bf16_f32 %0, %1, %2" : "=v"(w1) : "v"(p2), "v"(p3));
        unsigned* prow = (unsigned*)&pw[(quad * 4 + r) * 72];
        prow[l15] = w0;        // k' = 2*l15, 2*l15+1        (cols l15, l15+16)
        prow[16 + l15] = w1;   // k' = 32+2*l15, 32+2*l15+1  (cols l15+32, l15+48)
      }
    } else {          // diag tile: mask key > q
#pragma unroll
      for (int r = 0; r < 4; ++r) {
        const int q = q0 + quad * 4 + r;
        float pr[4];
#pragma unroll
        for (int nt = 0; nt < 4; ++nt) {
          float sv = s[nt][r] * scale2;
          if (key0 + nt * 16 + l15 > q) sv = -INFINITY;
          pr[nt] = __builtin_amdgcn_exp2f(sv);  // v_exp_f32(-inf)=0
        }
        lsum[r] += (pr[0] + pr[1]) + (pr[2] + pr[3]);
        unsigned w0, w1;
        asm("v_cvt_pk_bf16_f32 %0, %1, %2" : "=v"(w0) : "v"(pr[0]), "v"(pr[1]));
        asm("v_cvt_pk_bf16_f32 %0, %1, %2" : "=v"(w1) : "v"(pr[2]), "v"(pr[3]));
        unsigned* prow = (unsigned*)&pw[(quad * 4 + r) * 72];
        prow[l15] = w0;
        prow[16 + l15] = w1;
      }
    }
    asm volatile("s_waitcnt lgkmcnt(0)" ::: "memory");
#pragma unroll
    for (int kf = 0; kf < 2; ++kf) {
      const shortx8 pa = *(const shortx8*)&Ps[wid][l15 * 72 + kf * 32 + quad * 8];
#pragma unroll
      for (int dt = 0; dt < 4; ++dt) {
        const shortx8 vb = *(const shortx8*)&Vt[(dt * 16 + l15) * 72 + kf * 32 + quad * 8];
        o[dt] = __builtin_amdgcn_mfma_f32_16x16x32_bf16(pa, vb, o[dt], 0, 0, 0);
      }
    }
  }
  // reduce lsum over the 16 lanes of each quad group
  float ls[4];
#pragma unroll
  for (int r = 0; r < 4; ++r) {
    float s = lsum[r];
    for (int off = 1; off < 16; off <<= 1) s += __shfl_xor(s, off);
    ls[r] = s;
  }
  if (x < 8) {  // single chunk -> final output
    float inv[4];
#pragma unroll
    for (int r = 0; r < 4; ++r) inv[r] = __builtin_amdgcn_rcpf(ls[r]);
#pragma unroll
    for (int dt = 0; dt < 4; ++dt)
#pragma unroll
      for (int r = 0; r < 4; ++r) {
        const int q = q0 + quad * 4 + r;
        y[((size_t)b * T + q) * C + h * HD + dt * 16 + l15] =
            f2bf(o[dt][r] * inv[r]);
      }
  } else {      // bf16 O partials + fp32 lsum
    short* pp = (short*)part +
                ((size_t)(b * 16 + h) * ATTN_SLOTS + x) * ATTN_SLOT_SH;
    float* pl = (float*)(pp + 4096);
    const int qw = wid * 16;
#pragma unroll
    for (int dt = 0; dt < 4; ++dt)
#pragma unroll
      for (int r = 0; r < 4; ++r)
        pp[(qw + quad * 4 + r) * 64 + dt * 16 + l15] = f2bf(o[dt][r]);
    if (l15 == 0)
#pragma unroll
      for (int r = 0; r < 4; ++r)
        pl[qw + quad * 4 + r] = ls[r];
  }
}

__global__ __launch_bounds__(256)
void attn_reduce(const float* __restrict__ part, short* __restrict__ y) {
  constexpr int T = 2048, C = 1024;
  const int qb = 8 + blockIdx.x, h = blockIdx.y, b = blockIdx.z;
  const int c = qb / 8 + 1;  // 2..4 chunks
  int slot0;
  if (qb < 16)      slot0 = 8 + 2 * (qb - 8);
  else if (qb < 24) slot0 = 24 + 3 * (qb - 16);
  else              slot0 = 48 + 4 * (qb - 24);
  const short* rb = (const short*)part +
                    ((size_t)(b * 16 + h) * ATTN_SLOTS + slot0) * ATTN_SLOT_SH;
  const int t = threadIdx.x;
  const int q = t >> 2, dg = (t & 3) * 16;
  float acc[16] = {};
  float ls = 0.f;
  for (int ci = 0; ci < c; ++ci) {
    const short* pp = rb + (size_t)ci * ATTN_SLOT_SH;
    const shortx8 v0 = *(const shortx8*)(pp + q * 64 + dg);
    const shortx8 v1 = *(const shortx8*)(pp + q * 64 + dg + 8);
#pragma unroll
    for (int i = 0; i < 8; ++i) {
      acc[i] += bf2f(v0[i]);
      acc[8 + i] += bf2f(v1[i]);
    }
    ls += *(const float*)(pp + 4096 + 2 * q);
  }
  const float inv = __builtin_amdgcn_rcpf(ls);
  short o16[16];
#pragma unroll
  for (int i = 0; i < 16; ++i) o16[i] = f2bf(acc[i] * inv);
  short* yp = y + ((size_t)b * T + qb * 64 + q) * C + h * 64 + dg;
  *(shortx8*)yp = *(shortx8*)&o16[0];
  *(shortx8*)(yp + 8) = *(shortx8*)&o16[8];
}

// ---- fallback single-pass attention (used only if ws too small) ----
__global__ __launch_bounds__(256)
void attention_kernel(const short* __restrict__ qkv, short* __restrict__ y) {
  constexpr int T = 2048, C = 1024, HD = 64, S3 = 3072;
  __shared__ short Ks[64 * 72];
  __shared__ short Vt[64 * 72];
  __shared__ short Ps[4][16 * 72];
  const int qb = blockIdx.x, h = blockIdx.y, b = blockIdx.z;
  const int tid = threadIdx.x, wid = tid >> 6, lane = tid & 63;
  const int quad = lane >> 4, l15 = lane & 15;
  const size_t base = (size_t)b * T * S3;
  const int q0 = qb * 64 + wid * 16;
  const short* Qp = qkv + base + (size_t)(q0 + l15) * S3 + h * HD;
  const shortx8 qf0 = *(const shortx8*)(Qp + quad * 8);
  const shortx8 qf1 = *(const shortx8*)(Qp + 32 + quad * 8);
  floatx4 o[4] = {};
  float lsum[4] = {0.f, 0.f, 0.f, 0.f};
  const float scale2 = 0.03125f * 1.44269504088896f;
  const int skey = tid >> 2, sd = (tid & 3) * 16;
  const int vkp = tid & 31, vdb = tid >> 5;
  for (int kt = 0; kt <= qb; ++kt) {
    const int key0 = kt * 64;
    __syncthreads();
    {
      const short* Kp = qkv + base + (size_t)(key0 + skey) * S3 + C + h * HD + sd;
      shortx8 ka = *(const shortx8*)Kp;
      shortx8 kb = *(const shortx8*)(Kp + 8);
      *(shortx8*)&Ks[skey * 72 + sd] = ka;
      *(shortx8*)&Ks[skey * 72 + sd + 8] = kb;
      const short* Vp = qkv + base + (size_t)(key0 + 2 * vkp) * S3 + 2 * C + h * HD + vdb * 8;
      shortx8 va = *(const shortx8*)Vp;
      shortx8 vb = *(const shortx8*)(Vp + S3);
#pragma unroll
      for (int j = 0; j < 8; ++j) {
        short2 pr = make_short2(va[j], vb[j]);
        *(short2*)&Vt[(vdb * 8 + j) * 72 + 2 * vkp] = pr;
      }
    }
    __syncthreads();
    floatx4 s[4];
#pragma unroll
    for (int nt = 0; nt < 4; ++nt) {
      const short* kb = &Ks[(nt * 16 + l15) * 72 + quad * 8];
      floatx4 a = {};
      a = __builtin_amdgcn_mfma_f32_16x16x32_bf16(qf0, *(const shortx8*)kb, a, 0, 0, 0);
      a = __builtin_amdgcn_mfma_f32_16x16x32_bf16(qf1, *(const shortx8*)(kb + 32), a, 0, 0, 0);
      s[nt] = a;
    }
    short* pw = &Ps[wid][0];
    const bool diag = (kt == qb);
#pragma unroll
    for (int nt = 0; nt < 4; ++nt)
#pragma unroll
      for (int r = 0; r < 4; ++r) {
        float sv = s[nt][r] * scale2;
        if (diag) {
          const int key = key0 + nt * 16 + l15;
          const int q = q0 + quad * 4 + r;
          if (key > q) sv = -INFINITY;
        }
        const float p = __builtin_amdgcn_exp2f(sv);
        lsum[r] += p;
        pw[(quad * 4 + r) * 72 + nt * 16 + l15] = f2bf(p);
      }
    asm volatile("s_waitcnt lgkmcnt(0)" ::: "memory");
#pragma unroll
    for (int kf = 0; kf < 2; ++kf) {
      const shortx8 pa = *(const shortx8*)&Ps[wid][l15 * 72 + kf * 32 + quad * 8];
#pragma unroll
      for (int dt = 0; dt < 4; ++dt) {
        const shortx8 vb = *(const shortx8*)&Vt[(dt * 16 + l15) * 72 + kf * 32 + quad * 8];
        o[dt] = __builtin_amdgcn_mfma_f32_16x16x32_bf16(pa, vb, o[dt], 0, 0, 0);
      }
    }
  }
  float inv[4];
#pragma unroll
  for (int r = 0; r < 4; ++r) {
    float s = lsum[r];
    for (int off = 1; off < 16; off <<= 1) s += __shfl_xor(s, off);
    inv[r] = __builtin_amdgcn_rcpf(s);
  }
#pragma unroll
  for (int dt = 0; dt < 4; ++dt)
#pragma unroll
    for (int r = 0; r < 4; ++r) {
      const int q = q0 + quad * 4 + r;
      y[((size_t)b * T + q) * C + h * HD + dt * 16 + l15] = f2bf(o[dt][r] * inv[r]);
    }
}

extern "C" void kernel_launch(void* const* d_in, const int* in_sizes, int n_in,
                              void* d_out, int out_size, void* d_ws, size_t ws_size,
                              hipStream_t stream) {
  const float* x      = (const float*)d_in[0];
  const float* ln1_w  = (const float*)d_in[1];
  const float* ln1_b  = (const float*)d_in[2];
  const float* qkv_w  = (const float*)d_in[3];
  const float* qkv_b  = (const float*)d_in[4];
  const float* proj_w = (const float*)d_in[5];
  const float* proj_b = (const float*)d_in[6];
  const float* ln2_w  = (const float*)d_in[7];
  const float* ln2_b  = (const float*)d_in[8];
  const float* ff_w1  = (const float*)d_in[9];
  const float* ff_b1  = (const float*)d_in[10];
  const float* ff_w2  = (const float*)d_in[11];
  const float* ff_b2  = (const float*)d_in[12];
  float* out = (float*)d_out;

  char* p = (char*)d_ws;
  short* wT_qkv  = (short*)p; p += (size_t)3072 * 1024 * 2;
  short* wT_proj = (short*)p; p += (size_t)1024 * 1024 * 2;
  short* wT_ff1  = (short*)p; p += (size_t)4096 * 1024 * 2;
  short* wT_ff2  = (short*)p; p += (size_t)1024 * 4096 * 2;
  short* act16   = (short*)p; p += (size_t)8192 * 1024 * 2;  // h -> y -> h2
  short* big     = (short*)p; p += (size_t)8192 * 4096 * 2;  // qkv -> ff act
  float* part    = (float*)p;  // attn partials (43 MB, bf16 O + fp32 lsum)
  const size_t need = (size_t)(p - (char*)d_ws) +
                      (size_t)64 * ATTN_SLOTS * ATTN_SLOT_SH * 2;
  const bool split = (ws_size >= need);

  // weights -> bf16 transposed [N][K]
  transpose_cast<<<dim3(96, 32), 256, 0, stream>>>(qkv_w, wT_qkv, 1024, 3072);
  transpose_cast<<<dim3(32, 32), 256, 0, stream>>>(proj_w, wT_proj, 1024, 1024);
  transpose_cast<<<dim3(128, 32), 256, 0, stream>>>(ff_w1, wT_ff1, 1024, 4096);
  transpose_cast<<<dim3(32, 128), 256, 0, stream>>>(ff_w2, wT_ff2, 4096, 1024);

  // h = LN1(x)
  layernorm_kernel<<<8192, 256, 0, stream>>>(x, ln1_w, ln1_b, act16);
  // qkv = h @ qkv_w + qkv_b           [8192,3072]
  gemm_bt<0, short><<<dim3(24, 64), 256, 0, stream>>>(
      act16, 1024, wT_qkv, 1024, qkv_b, nullptr, big, 8192, 3072, 1024);
  // y = causal_attention(qkv)  — split-K if ws fits, else single-pass
  if (split) {
    attention_chunk<<<dim3(ATTN_SLOTS, 16, 4), 256, 0, stream>>>(big, act16, part);
    attn_reduce<<<dim3(24, 16, 4), 256, 0, stream>>>(part, act16);
  } else {
    attention_kernel<<<dim3(32, 16, 4), 256, 0, stream>>>(big, act16);
  }
  // x2 = x + y @ proj_w + proj_b  -> d_out (fp32)
  gemm_bt<2, float><<<dim3(8, 64), 256, 0, stream>>>(
      act16, 1024, wT_proj, 1024, proj_b, x, out, 8192, 1024, 1024);
  // h2 = LN2(x2)
  layernorm_kernel<<<8192, 256, 0, stream>>>(out, ln2_w, ln2_b, act16);
  // a = relu(h2 @ ff_w1 + ff_b1)      [8192,4096]
  gemm_bt<1, short><<<dim3(32, 64), 256, 0, stream>>>(
      act16, 1024, wT_ff1, 1024, ff_b1, nullptr, big, 8192, 4096, 1024);
  // out = x2 + a @ ff_w2 + ff_b2  — BK=128 (16 iters; resid
  // read-before-write, same thread)
  gemm_bt_k128<2, float><<<dim3(8, 64), 256, 0, stream>>>(
      big, 4096, wT_ff2, 4096, ff_b2, out, out, 8192, 1024, 4096);
}